// Round 5
// baseline (49310.455 us; speedup 1.0000x reference)
//
#include <hip/hip_runtime.h>
#include <stdint.h>

#define NB    256   // batch / segments
#define CIN   128   // input channels
#define HID   256   // hidden
#define TST   256   // only first 256 timesteps matter for the output
#define NCLS  400

#define GRPS  16    // batch groups
#define MEMB  16    // blocks per group (hidden-slice members)
#define BPG   16    // batches per group
#define RPB   64    // gate-rows per block (4 gates x 16 hid)
#define HPB   16    // hidden units per block
#define KQ    4     // K-quarters
#define KPT   96    // weight floats per thread (384/KQ)
#define HXP   392   // s_hx row stride in floats (16B-aligned, breaks bank patterns)
#define SPD   20    // s_part row stride in floats (16B-aligned)

// ---- workspace layout (bytes) ----
#define WS_SUMS   0u                       // 256*128*4   = 131072
#define WS_HBUF   131072u                  // 2*256*256*4 = 524288  (double-buffered h)
#define WS_C0     655360u                  // 256*256*4   = 262144
#define WS_CTRS   917504u                  // 16*4 group barrier counters
#define WS_PP     1048576u                 // 256*16*16*16*4 = 4194304 masked partials

__device__ __forceinline__ float sigm(float v) { return 1.0f / (1.0f + __expf(-v)); }
__device__ __forceinline__ float tanh_(float v) {
  v = fminf(fmaxf(v, -15.0f), 15.0f);
  const float e = __expf(2.0f * v);
  return (e - 1.0f) / (e + 1.0f);
}

// ---------------- segment sums (the "input_means" that are really sums) ----------------
__global__ void k_segsum(const float* __restrict__ x, const int* __restrict__ lens,
                         float* __restrict__ sums) {
  const int b = blockIdx.x, t = threadIdx.x;
  __shared__ int   s_l[NB];
  __shared__ int   s_red[256];
  __shared__ float s_f[CIN];
  s_l[t] = lens[t];
  __syncthreads();
  int part = 0;
  for (int i = t; i < b; i += 256) part += s_l[i];
  s_red[t] = part; __syncthreads();
  for (int k = 128; k > 0; k >>= 1) { if (t < k) s_red[t] += s_red[t + k]; __syncthreads(); }
  const int off = s_red[0];
  const int len = s_l[b];
  const int c = t & 127, half = t >> 7;
  float a = 0.f;
  for (int r = half; r < len; r += 2) a += x[(size_t)(off + r) * CIN + c];
  if (half) s_f[c] = a;
  __syncthreads();
  if (!half) sums[b * CIN + c] = a + s_f[c];
}

// ---------------- h0 = relu(sums@W1h^T)@W2h^T ; c0 likewise ----------------
__global__ void k_init(const float* __restrict__ sums,
                       const float* __restrict__ w1h, const float* __restrict__ w2h,
                       const float* __restrict__ w1c, const float* __restrict__ w2c,
                       float* __restrict__ hbuf, float* __restrict__ c0) {
  const int b = blockIdx.x, t = threadIdx.x;
  __shared__ float s_in[CIN], s_h[CIN], s_c[CIN];
  if (t < CIN) s_in[t] = sums[b * CIN + t];
  __syncthreads();
  {
    const int j = t & 127;
    const float* w = (t < CIN ? w1h : w1c) + j * CIN;
    float a = 0.f;
    #pragma unroll 8
    for (int k = 0; k < CIN; k++) a += s_in[k] * w[k];
    a = fmaxf(a, 0.f);
    if (t < CIN) s_h[j] = a; else s_c[j] = a;
  }
  __syncthreads();
  float ah = 0.f, ac = 0.f;
  const float* wh = w2h + t * CIN;
  const float* wc = w2c + t * CIN;
  #pragma unroll 8
  for (int k = 0; k < CIN; k++) { ah += s_h[k] * wh[k]; ac += s_c[k] * wc[k]; }
  hbuf[b * HID + t] = ah;   // buffer 0 = h_0
  c0[b * HID + t]   = ac;
}

// ---------------- persistent LSTM recurrence ----------------
// 256 blocks = 16 batch-groups (16 batches) x 16 members (16 hid = 64 gate rows).
// Thread = (gate-row r in 0..63, K-quarter kq): 96 weight floats in VGPRs.
// REGISTER-CAP HISTORY:
//   R1: 256 thr, 384 w/t -> cap 256, spill (10 GB refetch)
//   R2: 256 thr, 192 w/t -> cap 256, ~150 spilled (10 GB refetch)
//   R3: 512 thr, 96 w/t, bounds(512,2) -> cap 128, in-loop spill (120 GB)
//   R4: 512 thr, 96 w/t, bounds(512,1) -> STILL cap 128 (bounds ignored for 8-wave blocks)
//   R5: 256 thr, 96 w/t, bounds(256,1) -> the shape that provably got 256; need ~150.
__launch_bounds__(256, 1)
__global__ void k_lstm(const float* __restrict__ x, const int* __restrict__ lens,
                       const float* __restrict__ Wih, const float* __restrict__ Whh,
                       const float* __restrict__ bih, const float* __restrict__ bhh,
                       const float* __restrict__ c0,
                       float* __restrict__ hbuf, float* __restrict__ pp,
                       int* __restrict__ ctrs) {
  const int p    = blockIdx.x;
  const int m    = p >> 4;            // member 0..15 (hidden slice)
  const int grp  = p & 15;            // batch group 0..15 (members stride 16 -> same XCD slot)
  const int bat0 = grp * BPG;
  const int hid0 = m * HPB;

  const int t  = threadIdx.x;
  const int r  = t & 63;              // local gate-row 0..63
  const int kq = t >> 6;              // K-quarter 0..3 (wave-uniform)
  const int gidx = r >> 4, j = r & 15;
  const int row = gidx * HID + hid0 + j;        // global gate row

  const int j2 = t & 15, b2 = t >> 4;           // update role: (hid j2, batch b2) 16x16
  const int ch = t & 127, bh = t >> 7;          // x staging: channel + batch-octet

  __shared__ float s_hx[BPG * HXP];             // [16 b][392] = 25 KB, batch-major
  __shared__ float s_part[KQ * RPB * SPD];      // 4*64*20 = 20 KB quarter partials
  __shared__ float s_red[256];
  __shared__ int   s_lens[NB];
  __shared__ int   s_off[BPG], s_len[BPG];

  s_lens[t] = lens[t];
  __syncthreads();
  if (t < BPG) {
    int off = 0;
    for (int k = 0; k < bat0 + t; k++) off += s_lens[k];
    s_off[t] = off;
    s_len[t] = s_lens[bat0 + t];
  }
  __syncthreads();

  // ---- persistent weights: 96 fp32 in VGPRs (static indices after unroll) ----
  float w[KPT];
  {
    const int k0 = kq * KPT;
    #pragma unroll
    for (int q = 0; q < KPT / 4; q++) {
      const int k = k0 + q * 4;
      float4 v;
      if (k < CIN) v = *(const float4*)(Wih + (size_t)row * CIN + k);
      else         v = *(const float4*)(Whh + (size_t)row * HID + (k - CIN));
      w[q*4+0] = v.x; w[q*4+1] = v.y; w[q*4+2] = v.z; w[q*4+3] = v.w;
    }
  }
  const float bias = (kq == 0) ? (bih[row] + bhh[row]) : 0.f;

  float c_reg = c0[(size_t)(bat0 + b2) * HID + hid0 + j2];

  float xp[8];
  auto prefx = [&](int s) {
    #pragma unroll
    for (int i = 0; i < 8; i++) {
      const int b = bh * 8 + i;
      xp[i] = (s < s_len[b]) ? x[(size_t)(s_off[b] + s) * CIN + ch] : 0.f;
    }
  };
  auto stage = [&](int s) {
    #pragma unroll
    for (int i = 0; i < 8; i++)                  // x: lanes write consecutive -> no conflict
      s_hx[(bh * 8 + i) * HXP + ch] = xp[i];
    const float* hb = hbuf + (size_t)(s & 1) * NB * HID + t;   // t = hidden index k
    #pragma unroll
    for (int b = 0; b < BPG; b++)                // reads coalesced; writes conflict-free
      s_hx[b * HXP + CIN + t] = hb[(size_t)(bat0 + b) * HID];
  };

  prefx(0);
  stage(0);
  __syncthreads();

  for (int s = 0; s < TST; s++) {
    // ---- gate quarter-partials: 96 K x 16 batches; hx reads are wave-uniform b128 bcasts ----
    float acc[BPG];
    #pragma unroll
    for (int b = 0; b < BPG; b++) acc[b] = bias;
    {
      const float4* hx4 = (const float4*)s_hx;   // row b starts at b*98 float4s
      const int kb4 = kq * (KPT / 4);
      #pragma unroll
      for (int kk = 0; kk < KPT / 4; kk++) {
        const float w0 = w[4*kk+0], w1 = w[4*kk+1], w2 = w[4*kk+2], w3 = w[4*kk+3];
        #pragma unroll
        for (int b = 0; b < BPG; b++) {
          const float4 v = hx4[b * (HXP/4) + kb4 + kk];
          acc[b] = fmaf(w0, v.x, fmaf(w1, v.y, fmaf(w2, v.z, fmaf(w3, v.w, acc[b]))));
        }
      }
    }
    if (s < TST - 1) prefx(s + 1);   // x loads drain during update/barrier

    {
      float* sp = s_part + (size_t)(kq * RPB + r) * SPD;
      *(float4*)(sp +  0) = make_float4(acc[0],  acc[1],  acc[2],  acc[3]);
      *(float4*)(sp +  4) = make_float4(acc[4],  acc[5],  acc[6],  acc[7]);
      *(float4*)(sp +  8) = make_float4(acc[8],  acc[9],  acc[10], acc[11]);
      *(float4*)(sp + 12) = make_float4(acc[12], acc[13], acc[14], acc[15]);
    }
    __syncthreads();

    // ---- update thread reduces its own 4 gate rows over the 4 K-quarters ----
    float gv[4];
    #pragma unroll
    for (int g = 0; g < 4; g++) {
      float a = 0.f;
      #pragma unroll
      for (int q = 0; q < KQ; q++)
        a += s_part[(size_t)(q * RPB + g * HPB + j2) * SPD + b2];
      gv[g] = a;
    }
    c_reg = fmaf(sigm(gv[1]), c_reg, sigm(gv[0]) * tanh_(gv[2]));
    const float h = sigm(gv[3]) * tanh_(c_reg);

    hbuf[(size_t)((s + 1) & 1) * NB * HID + (size_t)(bat0 + b2) * HID + hid0 + j2] = h;
    s_red[b2 * HPB + j2] = (bat0 + b2 < s_lens[s]) ? h : 0.f;

    __threadfence();                 // make h stores visible before arrive
    __syncthreads();

    // masked partial for output row s (wave 1: overlaps wave 0's barrier spin)
    if (t >= 64 && t < 64 + HPB) {
      const int jl = t - 64;
      float ps = 0.f;
      #pragma unroll
      for (int b = 0; b < BPG; b++) ps += s_red[b * HPB + jl];
      pp[(((size_t)s * GRPS + grp) * MEMB + m) * HPB + jl] = ps;
    }

    if (s == TST - 1) break;

    // ---- 16-block group barrier: release arrive, relaxed spin + sleep, one acquire ----
    if (t == 0) {
      __hip_atomic_fetch_add(ctrs + grp, 1, __ATOMIC_RELEASE, __HIP_MEMORY_SCOPE_AGENT);
      const int target = MEMB * (s + 1);
      while (__hip_atomic_load(ctrs + grp, __ATOMIC_RELAXED, __HIP_MEMORY_SCOPE_AGENT) < target)
        __builtin_amdgcn_s_sleep(2);
      (void)__hip_atomic_load(ctrs + grp, __ATOMIC_ACQUIRE, __HIP_MEMORY_SCOPE_AGENT);
    }
    __syncthreads();
    stage(s + 1);
    __syncthreads();
  }
}

// ---------------- masked batch-mean + FC ----------------
__global__ void k_out(const float* __restrict__ pp, const int* __restrict__ lens,
                      const float* __restrict__ fcW, const float* __restrict__ fcb,
                      float* __restrict__ out) {
  const int i = blockIdx.x, t = threadIdx.x;
  __shared__ float s_fc[HID];
  const int cnt = min(lens[i], NB);
  const int m = t >> 4, jl = t & 15;             // hid = t
  float a = 0.f;
  const float* base = pp + ((size_t)i * GRPS * MEMB + m) * HPB + jl;
  #pragma unroll 4
  for (int g = 0; g < GRPS; g++) a += base[(size_t)g * MEMB * HPB];
  s_fc[t] = a / (float)cnt;
  __syncthreads();
  for (int n = t; n < NCLS; n += 256) {
    float acc = fcb[n];
    const float4* w4 = (const float4*)(fcW + (size_t)n * HID);
    #pragma unroll 8
    for (int k4 = 0; k4 < HID / 4; k4++) {
      const float4 w = w4[k4];
      acc = fmaf(s_fc[4*k4+0], w.x, acc);
      acc = fmaf(s_fc[4*k4+1], w.y, acc);
      acc = fmaf(s_fc[4*k4+2], w.z, acc);
      acc = fmaf(s_fc[4*k4+3], w.w, acc);
    }
    out[(size_t)i * NCLS + n] = acc;
  }
}

extern "C" void kernel_launch(void* const* d_in, const int* in_sizes, int n_in,
                              void* d_out, int out_size, void* d_ws, size_t ws_size,
                              hipStream_t stream) {
  const float* x    = (const float*)d_in[0];
  const int*   lens = (const int*)  d_in[1];
  const float* Wih  = (const float*)d_in[2];
  const float* Whh  = (const float*)d_in[3];
  const float* bih  = (const float*)d_in[4];
  const float* bhh  = (const float*)d_in[5];
  const float* w1h  = (const float*)d_in[6];
  const float* w2h  = (const float*)d_in[7];
  const float* w1c  = (const float*)d_in[8];
  const float* w2c  = (const float*)d_in[9];
  const float* fcW  = (const float*)d_in[10];
  const float* fcb  = (const float*)d_in[11];
  float* out = (float*)d_out;

  char* ws = (char*)d_ws;
  float* sums = (float*)(ws + WS_SUMS);
  float* hbuf = (float*)(ws + WS_HBUF);
  float* c0   = (float*)(ws + WS_C0);
  int*   ctrs = (int*)  (ws + WS_CTRS);
  float* pp   = (float*)(ws + WS_PP);

  hipMemsetAsync(ctrs, 0, GRPS * sizeof(int), stream);  // barrier counters zeroed every call
  k_segsum<<<NB, 256, 0, stream>>>(x, lens, sums);
  k_init  <<<NB, 256, 0, stream>>>(sums, w1h, w2h, w1c, w2c, hbuf, c0);
  k_lstm  <<<NB, 256, 0, stream>>>(x, lens, Wih, Whh, bih, bhh, c0, hbuf, pp, ctrs);
  k_out   <<<NB, 256, 0, stream>>>(pp, lens, fcW, fcb, out);
}

// Round 6
// 48598.502 us; speedup vs baseline: 1.0146x; 1.0146x over previous
//
#include <hip/hip_runtime.h>
#include <stdint.h>

#define NB    256   // batch / segments
#define CIN   128   // input channels
#define HID   256   // hidden
#define TST   256   // only first 256 timesteps matter for the output
#define NCLS  400

#define GRPS  16    // batch groups
#define MEMB  16    // blocks per group (hidden-slice members)
#define BPG   16    // batches per group
#define RPB   64    // gate-rows per block (4 gates x 16 hid)
#define HPB   16    // hidden units per block
#define KQ    4     // K-quarters (kq = wave id)
#define KPT   96    // K per thread (384/KQ)
#define HXP   392   // s_hx row stride (floats)
#define SWP   388   // s_w row stride (floats): 97 quad-units == 1 mod 8 -> even bank spread
#define SPD   20    // s_part row stride (floats)

// ---- workspace layout (bytes) ----
#define WS_SUMS   0u                       // 256*128*4   = 131072
#define WS_HBUF   131072u                  // 2*256*256*4 = 524288  (double-buffered h)
#define WS_C0     655360u                  // 256*256*4   = 262144
#define WS_CTRS   917504u                  // 16*4 group barrier counters
#define WS_PP     1048576u                 // 256*16*16*16*4 = 4194304 masked partials

__device__ __forceinline__ float sigm(float v) { return 1.0f / (1.0f + __expf(-v)); }
__device__ __forceinline__ float tanh_(float v) {
  v = fminf(fmaxf(v, -15.0f), 15.0f);
  const float e = __expf(2.0f * v);
  return (e - 1.0f) / (e + 1.0f);
}

// ---------------- segment sums (the "input_means" that are really sums) ----------------
__global__ void k_segsum(const float* __restrict__ x, const int* __restrict__ lens,
                         float* __restrict__ sums) {
  const int b = blockIdx.x, t = threadIdx.x;
  __shared__ int   s_l[NB];
  __shared__ int   s_red[256];
  __shared__ float s_f[CIN];
  s_l[t] = lens[t];
  __syncthreads();
  int part = 0;
  for (int i = t; i < b; i += 256) part += s_l[i];
  s_red[t] = part; __syncthreads();
  for (int k = 128; k > 0; k >>= 1) { if (t < k) s_red[t] += s_red[t + k]; __syncthreads(); }
  const int off = s_red[0];
  const int len = s_l[b];
  const int c = t & 127, half = t >> 7;
  float a = 0.f;
  for (int r = half; r < len; r += 2) a += x[(size_t)(off + r) * CIN + c];
  if (half) s_f[c] = a;
  __syncthreads();
  if (!half) sums[b * CIN + c] = a + s_f[c];
}

// ---------------- h0 = relu(sums@W1h^T)@W2h^T ; c0 likewise ----------------
__global__ void k_init(const float* __restrict__ sums,
                       const float* __restrict__ w1h, const float* __restrict__ w2h,
                       const float* __restrict__ w1c, const float* __restrict__ w2c,
                       float* __restrict__ hbuf, float* __restrict__ c0) {
  const int b = blockIdx.x, t = threadIdx.x;
  __shared__ float s_in[CIN], s_h[CIN], s_c[CIN];
  if (t < CIN) s_in[t] = sums[b * CIN + t];
  __syncthreads();
  {
    const int j = t & 127;
    const float* w = (t < CIN ? w1h : w1c) + j * CIN;
    float a = 0.f;
    #pragma unroll 8
    for (int k = 0; k < CIN; k++) a += s_in[k] * w[k];
    a = fmaxf(a, 0.f);
    if (t < CIN) s_h[j] = a; else s_c[j] = a;
  }
  __syncthreads();
  float ah = 0.f, ac = 0.f;
  const float* wh = w2h + t * CIN;
  const float* wc = w2c + t * CIN;
  #pragma unroll 8
  for (int k = 0; k < CIN; k++) { ah += s_h[k] * wh[k]; ac += s_c[k] * wc[k]; }
  hbuf[b * HID + t] = ah;   // buffer 0 = h_0
  c0[b * HID + t]   = ac;
}

// ---------------- persistent LSTM recurrence ----------------
// 256 blocks = 16 batch-groups (16 batches) x 16 members (16 hid = 64 gate rows).
// WEIGHTS LIVE IN LDS (99.3 KB/block), not VGPRs.
// REGISTER-CAP HISTORY: R1-R5 all spilled persistent weight arrays (96..384 floats/thread)
// regardless of launch bounds/block shape -> 10-120 GB scratch traffic. hipcc will not
// hold ~100-float arrays in regs next to 16 live accumulators. LDS is the residence class.
__launch_bounds__(256, 1)
__global__ void k_lstm(const float* __restrict__ x, const int* __restrict__ lens,
                       const float* __restrict__ Wih, const float* __restrict__ Whh,
                       const float* __restrict__ bih, const float* __restrict__ bhh,
                       const float* __restrict__ c0,
                       float* __restrict__ hbuf, float* __restrict__ pp,
                       int* __restrict__ ctrs) {
  const int p    = blockIdx.x;
  const int m    = p >> 4;            // member 0..15 (hidden slice)
  const int grp  = p & 15;            // batch group 0..15
  const int bat0 = grp * BPG;
  const int hid0 = m * HPB;

  const int t  = threadIdx.x;
  const int r  = t & 63;              // local gate-row 0..63
  const int kq = t >> 6;              // K-quarter == wave id (wave-uniform)
  const int gidx = r >> 4, j = r & 15;
  const int row = gidx * HID + hid0 + j;        // global gate row

  const int j2 = t & 15, b2 = t >> 4;           // update role: (hid j2, batch b2) 16x16
  const int ch = t & 127, bh = t >> 7;          // x staging: channel + batch-octet

  __shared__ float s_w[RPB * SWP];              // 64 x 388 = 99.3 KB weight slice
  __shared__ float s_hx[BPG * HXP];             // [16 b][392] = 25 KB, batch-major
  __shared__ float s_part[KQ * RPB * SPD];      // 20 KB quarter partials
  __shared__ float s_red[256];
  __shared__ int   s_lens[NB];
  __shared__ int   s_off[BPG], s_len[BPG];

  s_lens[t] = lens[t];
  __syncthreads();
  if (t < BPG) {
    int off = 0;
    for (int k = 0; k < bat0 + t; k++) off += s_lens[k];
    s_off[t] = off;
    s_len[t] = s_lens[bat0 + t];
  }

  // ---- one-time: stage this block's 64x384 weight slice into LDS ----
  // 6144 float4 total; thread does 24, coalesced within each row segment.
  #pragma unroll
  for (int q = 0; q < 24; q++) {
    const int idx = q * 256 + t;            // float4 index
    const int lr  = idx / 96;               // local row 0..63 (96 float4 per row)
    const int kk4 = idx % 96;
    const int k   = kk4 * 4;
    const int grow = (lr >> 4) * HID + hid0 + (lr & 15);
    float4 v;
    if (k < CIN) v = *(const float4*)(Wih + (size_t)grow * CIN + k);
    else         v = *(const float4*)(Whh + (size_t)grow * HID + (k - CIN));
    ((float4*)(s_w + (size_t)lr * SWP))[kk4] = v;
  }
  const float bias = (kq == 0) ? (bih[row] + bhh[row]) : 0.f;

  float c_reg = c0[(size_t)(bat0 + b2) * HID + hid0 + j2];

  float xp[8];
  auto prefx = [&](int s) {
    #pragma unroll
    for (int i = 0; i < 8; i++) {
      const int b = bh * 8 + i;
      xp[i] = (s < s_len[b]) ? x[(size_t)(s_off[b] + s) * CIN + ch] : 0.f;
    }
  };
  auto stage = [&](int s) {
    #pragma unroll
    for (int i = 0; i < 8; i++)
      s_hx[(bh * 8 + i) * HXP + ch] = xp[i];
    const float* hb = hbuf + (size_t)(s & 1) * NB * HID + t;   // t = hidden index k
    #pragma unroll
    for (int b = 0; b < BPG; b++)
      s_hx[b * HXP + CIN + t] = hb[(size_t)(bat0 + b) * HID];
  };

  prefx(0);
  stage(0);
  __syncthreads();

  for (int s = 0; s < TST; s++) {
    // ---- gate quarter-partials: w from LDS (per-lane b128, rows spread over banks),
    //      hx uniform-address b128 broadcasts (conflict-free by definition) ----
    float acc[BPG];
    #pragma unroll
    for (int b = 0; b < BPG; b++) acc[b] = bias;
    {
      const float4* wrow = (const float4*)(s_w + (size_t)r * SWP) + kq * (KPT / 4);
      const float4* hx4  = (const float4*)s_hx + kq * (KPT / 4);
      #pragma unroll
      for (int kk = 0; kk < KPT / 4; kk++) {
        const float4 wv = wrow[kk];
        #pragma unroll
        for (int b = 0; b < BPG; b++) {
          const float4 v = hx4[b * (HXP / 4) + kk];
          acc[b] = fmaf(wv.x, v.x, fmaf(wv.y, v.y, fmaf(wv.z, v.z, fmaf(wv.w, v.w, acc[b]))));
        }
      }
    }
    if (s < TST - 1) prefx(s + 1);   // x loads drain during update/barrier

    {
      float* sp = s_part + (size_t)(kq * RPB + r) * SPD;
      *(float4*)(sp +  0) = make_float4(acc[0],  acc[1],  acc[2],  acc[3]);
      *(float4*)(sp +  4) = make_float4(acc[4],  acc[5],  acc[6],  acc[7]);
      *(float4*)(sp +  8) = make_float4(acc[8],  acc[9],  acc[10], acc[11]);
      *(float4*)(sp + 12) = make_float4(acc[12], acc[13], acc[14], acc[15]);
    }
    __syncthreads();

    // ---- update thread reduces its own 4 gate rows over the 4 K-quarters ----
    float gv[4];
    #pragma unroll
    for (int g = 0; g < 4; g++) {
      float a = 0.f;
      #pragma unroll
      for (int q = 0; q < KQ; q++)
        a += s_part[(size_t)(q * RPB + g * HPB + j2) * SPD + b2];
      gv[g] = a;
    }
    c_reg = fmaf(sigm(gv[1]), c_reg, sigm(gv[0]) * tanh_(gv[2]));
    const float h = sigm(gv[3]) * tanh_(c_reg);

    hbuf[(size_t)((s + 1) & 1) * NB * HID + (size_t)(bat0 + b2) * HID + hid0 + j2] = h;
    s_red[b2 * HPB + j2] = (bat0 + b2 < s_lens[s]) ? h : 0.f;

    __threadfence();                 // make h stores visible before arrive
    __syncthreads();

    // masked partial for output row s (wave 1: overlaps wave 0's barrier spin)
    if (t >= 64 && t < 64 + HPB) {
      const int jl = t - 64;
      float ps = 0.f;
      #pragma unroll
      for (int b = 0; b < BPG; b++) ps += s_red[b * HPB + jl];
      pp[(((size_t)s * GRPS + grp) * MEMB + m) * HPB + jl] = ps;
    }

    if (s == TST - 1) break;

    // ---- 16-block group barrier: release arrive, relaxed spin + sleep, one acquire ----
    if (t == 0) {
      __hip_atomic_fetch_add(ctrs + grp, 1, __ATOMIC_RELEASE, __HIP_MEMORY_SCOPE_AGENT);
      const int target = MEMB * (s + 1);
      while (__hip_atomic_load(ctrs + grp, __ATOMIC_RELAXED, __HIP_MEMORY_SCOPE_AGENT) < target)
        __builtin_amdgcn_s_sleep(2);
      (void)__hip_atomic_load(ctrs + grp, __ATOMIC_ACQUIRE, __HIP_MEMORY_SCOPE_AGENT);
    }
    __syncthreads();
    stage(s + 1);
    __syncthreads();
  }
}

// ---------------- masked batch-mean + FC ----------------
__global__ void k_out(const float* __restrict__ pp, const int* __restrict__ lens,
                      const float* __restrict__ fcW, const float* __restrict__ fcb,
                      float* __restrict__ out) {
  const int i = blockIdx.x, t = threadIdx.x;
  __shared__ float s_fc[HID];
  const int cnt = min(lens[i], NB);
  const int m = t >> 4, jl = t & 15;             // hid = t
  float a = 0.f;
  const float* base = pp + ((size_t)i * GRPS * MEMB + m) * HPB + jl;
  #pragma unroll 4
  for (int g = 0; g < GRPS; g++) a += base[(size_t)g * MEMB * HPB];
  s_fc[t] = a / (float)cnt;
  __syncthreads();
  for (int n = t; n < NCLS; n += 256) {
    float acc = fcb[n];
    const float4* w4 = (const float4*)(fcW + (size_t)n * HID);
    #pragma unroll 8
    for (int k4 = 0; k4 < HID / 4; k4++) {
      const float4 w = w4[k4];
      acc = fmaf(s_fc[4*k4+0], w.x, acc);
      acc = fmaf(s_fc[4*k4+1], w.y, acc);
      acc = fmaf(s_fc[4*k4+2], w.z, acc);
      acc = fmaf(s_fc[4*k4+3], w.w, acc);
    }
    out[(size_t)i * NCLS + n] = acc;
  }
}

extern "C" void kernel_launch(void* const* d_in, const int* in_sizes, int n_in,
                              void* d_out, int out_size, void* d_ws, size_t ws_size,
                              hipStream_t stream) {
  const float* x    = (const float*)d_in[0];
  const int*   lens = (const int*)  d_in[1];
  const float* Wih  = (const float*)d_in[2];
  const float* Whh  = (const float*)d_in[3];
  const float* bih  = (const float*)d_in[4];
  const float* bhh  = (const float*)d_in[5];
  const float* w1h  = (const float*)d_in[6];
  const float* w2h  = (const float*)d_in[7];
  const float* w1c  = (const float*)d_in[8];
  const float* w2c  = (const float*)d_in[9];
  const float* fcW  = (const float*)d_in[10];
  const float* fcb  = (const float*)d_in[11];
  float* out = (float*)d_out;

  char* ws = (char*)d_ws;
  float* sums = (float*)(ws + WS_SUMS);
  float* hbuf = (float*)(ws + WS_HBUF);
  float* c0   = (float*)(ws + WS_C0);
  int*   ctrs = (int*)  (ws + WS_CTRS);
  float* pp   = (float*)(ws + WS_PP);

  hipMemsetAsync(ctrs, 0, GRPS * sizeof(int), stream);  // barrier counters zeroed every call
  k_segsum<<<NB, 256, 0, stream>>>(x, lens, sums);
  k_init  <<<NB, 256, 0, stream>>>(sums, w1h, w2h, w1c, w2c, hbuf, c0);
  k_lstm  <<<NB, 256, 0, stream>>>(x, lens, Wih, Whh, bih, bhh, c0, hbuf, pp, ctrs);
  k_out   <<<NB, 256, 0, stream>>>(pp, lens, fcW, fcb, out);
}

// Round 8
// 15792.992 us; speedup vs baseline: 3.1223x; 3.0772x over previous
//
#include <hip/hip_runtime.h>
#include <stdint.h>

#define NB    256   // batch / segments
#define CIN   128   // input channels
#define HID   256   // hidden
#define TST   256   // only first 256 timesteps matter for the output
#define NCLS  400

#define GRPS  16    // batch groups
#define MEMB  16    // blocks per group (hidden-slice members)
#define BPG   16    // batches per group
#define RPB   64    // gate-rows per block (4 gates x 16 hid)
#define HPB   16    // hidden units per block
#define SWP   388   // s_w row stride (floats): 97 quads (odd) -> rows cover all 8 bank-groups
#define HXP   396   // s_hx row stride (floats): 99 quads; 8-row stride == 0 mod 8 -> 2-way (free)
#define HXQ   (HXP/4)
#define SPD   20    // s_part row stride (floats)

// ---- workspace layout (bytes) ----
#define WS_SUMS   0u                       // 256*128*4   = 131072
#define WS_HBUF   131072u                  // 2*256*256*4 = 524288  (double-buffered h)
#define WS_C0     655360u                  // 256*256*4   = 262144
#define WS_CTRS   917504u                  // 16 ctrs padded to 64B = 1024
#define WS_PP     1048576u                 // 256*16*16*16*4 = 4194304 masked partials

__device__ __forceinline__ float sigm(float v) { return 1.0f / (1.0f + __expf(-v)); }
__device__ __forceinline__ float tanh_(float v) {
  v = fminf(fmaxf(v, -15.0f), 15.0f);
  const float e = __expf(2.0f * v);
  return (e - 1.0f) / (e + 1.0f);
}

// ---------------- segment sums (the "input_means" that are really sums) ----------------
__global__ void k_segsum(const float* __restrict__ x, const int* __restrict__ lens,
                         float* __restrict__ sums) {
  const int b = blockIdx.x, t = threadIdx.x;
  __shared__ int   s_l[NB];
  __shared__ int   s_red[256];
  __shared__ float s_f[CIN];
  s_l[t] = lens[t];
  __syncthreads();
  int part = 0;
  for (int i = t; i < b; i += 256) part += s_l[i];
  s_red[t] = part; __syncthreads();
  for (int k = 128; k > 0; k >>= 1) { if (t < k) s_red[t] += s_red[t + k]; __syncthreads(); }
  const int off = s_red[0];
  const int len = s_l[b];
  const int c = t & 127, half = t >> 7;
  float a = 0.f;
  for (int r = half; r < len; r += 2) a += x[(size_t)(off + r) * CIN + c];
  if (half) s_f[c] = a;
  __syncthreads();
  if (!half) sums[b * CIN + c] = a + s_f[c];
}

// ---------------- h0 = relu(sums@W1h^T)@W2h^T ; c0 likewise ----------------
__global__ void k_init(const float* __restrict__ sums,
                       const float* __restrict__ w1h, const float* __restrict__ w2h,
                       const float* __restrict__ w1c, const float* __restrict__ w2c,
                       float* __restrict__ hbuf, float* __restrict__ c0) {
  const int b = blockIdx.x, t = threadIdx.x;
  __shared__ float s_in[CIN], s_h[CIN], s_c[CIN];
  if (t < CIN) s_in[t] = sums[b * CIN + t];
  __syncthreads();
  {
    const int j = t & 127;
    const float* w = (t < CIN ? w1h : w1c) + j * CIN;
    float a = 0.f;
    #pragma unroll 8
    for (int k = 0; k < CIN; k++) a += s_in[k] * w[k];
    a = fmaxf(a, 0.f);
    if (t < CIN) s_h[j] = a; else s_c[j] = a;
  }
  __syncthreads();
  float ah = 0.f, ac = 0.f;
  const float* wh = w2h + t * CIN;
  const float* wc = w2c + t * CIN;
  #pragma unroll 8
  for (int k = 0; k < CIN; k++) { ah += s_h[k] * wh[k]; ac += s_c[k] * wc[k]; }
  hbuf[b * HID + t] = ah;   // buffer 0 = h_0
  c0[b * HID + t]   = ac;
}

// ---------------- persistent LSTM recurrence ----------------
// 256 blocks = 16 batch-groups (16 batches) x 16 members (16 hid = 64 gate rows).
// Weights in LDS (99.3 KB). Thread tile = 2 gate-rows x 8 batches x 96 K.
// NO THREAD-PRIVATE ARRAYS: R3-R6 all had float acc[16]/w[96]/xp[8] arrays ->
// hipcc kept them in scratch -> 70-120 GB of per-step private traffic (the
// entire 44-49 ms was HBM time on scratch). Named scalars ONLY in the hot loop.
// (R7 compile fix: macro params renamed -- parameter `w` collided with member `.w`.)
#define FMA4(A, Wv, Hv) A = fmaf((Wv).x, (Hv).x, fmaf((Wv).y, (Hv).y, fmaf((Wv).z, (Hv).z, fmaf((Wv).w, (Hv).w, (A)))))
__launch_bounds__(256, 1)
__global__ void k_lstm(const float* __restrict__ x, const int* __restrict__ lens,
                       const float* __restrict__ Wih, const float* __restrict__ Whh,
                       const float* __restrict__ bih, const float* __restrict__ bhh,
                       const float* __restrict__ c0,
                       float* __restrict__ hbuf, float* __restrict__ pp,
                       int* __restrict__ ctrs) {
  const int p    = blockIdx.x;
  const int m    = p >> 4;            // member 0..15 (hidden slice)
  const int grp  = p & 15;            // batch group 0..15
  const int bat0 = grp * BPG;
  const int hid0 = m * HPB;

  const int t   = threadIdx.x;
  const int kq  = t >> 6;             // K-quarter == wave id (wave-uniform)
  const int rp  = (t & 63) >> 1;      // row-pair 0..31
  const int bq  = t & 1;              // batch-octet 0..1
  const int r0  = rp * 2, r1 = r0 + 1;

  const int j2 = t & 15, b2 = t >> 4;           // update role: (hid j2, batch b2) 16x16
  const int ch = t & 127, bh8 = (t >> 7) * 8;   // x staging: channel + batch-octet

  __shared__ float s_w[RPB * SWP];              // 64 x 388 = 99.3 KB weight slice
  __shared__ float s_hx[BPG * HXP];             // 16 x 396 = 25.3 KB, batch-major
  __shared__ float s_part[4 * RPB * SPD];       // 20 KB quarter partials
  __shared__ float s_red[256];
  __shared__ int   s_lens[NB];
  __shared__ int   s_off[BPG], s_len[BPG];

  s_lens[t] = lens[t];
  __syncthreads();
  if (t < BPG) {
    int off = 0;
    for (int k = 0; k < bat0 + t; k++) off += s_lens[k];
    s_off[t] = off;
    s_len[t] = s_lens[bat0 + t];
  }

  // ---- one-time: stage this block's 64x384 weight slice into LDS ----
  #pragma unroll
  for (int q = 0; q < 24; q++) {
    const int idx = q * 256 + t;            // float4 index
    const int lr  = idx / 96;               // local row 0..63 (96 float4 per row)
    const int kk4 = idx % 96;
    const int k   = kk4 * 4;
    const int grow = (lr >> 4) * HID + hid0 + (lr & 15);
    float4 v;
    if (k < CIN) v = *(const float4*)(Wih + (size_t)grow * CIN + k);
    else         v = *(const float4*)(Whh + (size_t)grow * HID + (k - CIN));
    ((float4*)(s_w + (size_t)lr * SWP))[kk4] = v;
  }
  const int grow0 = (r0 >> 4) * HID + hid0 + (r0 & 15);
  const int grow1 = (r1 >> 4) * HID + hid0 + (r1 & 15);
  const float bias0 = (kq == 0) ? (bih[grow0] + bhh[grow0]) : 0.f;
  const float bias1 = (kq == 0) ? (bih[grow1] + bhh[grow1]) : 0.f;

  float c_reg = c0[(size_t)(bat0 + b2) * HID + hid0 + j2];

  float xp0, xp1, xp2, xp3, xp4, xp5, xp6, xp7;
  #define PREFX(S) do { \
    xp0 = ((S) < s_len[bh8+0]) ? x[(size_t)(s_off[bh8+0]+(S))*CIN+ch] : 0.f; \
    xp1 = ((S) < s_len[bh8+1]) ? x[(size_t)(s_off[bh8+1]+(S))*CIN+ch] : 0.f; \
    xp2 = ((S) < s_len[bh8+2]) ? x[(size_t)(s_off[bh8+2]+(S))*CIN+ch] : 0.f; \
    xp3 = ((S) < s_len[bh8+3]) ? x[(size_t)(s_off[bh8+3]+(S))*CIN+ch] : 0.f; \
    xp4 = ((S) < s_len[bh8+4]) ? x[(size_t)(s_off[bh8+4]+(S))*CIN+ch] : 0.f; \
    xp5 = ((S) < s_len[bh8+5]) ? x[(size_t)(s_off[bh8+5]+(S))*CIN+ch] : 0.f; \
    xp6 = ((S) < s_len[bh8+6]) ? x[(size_t)(s_off[bh8+6]+(S))*CIN+ch] : 0.f; \
    xp7 = ((S) < s_len[bh8+7]) ? x[(size_t)(s_off[bh8+7]+(S))*CIN+ch] : 0.f; \
  } while (0)
  #define STAGE(S) do { \
    s_hx[(bh8+0)*HXP+ch] = xp0; s_hx[(bh8+1)*HXP+ch] = xp1; \
    s_hx[(bh8+2)*HXP+ch] = xp2; s_hx[(bh8+3)*HXP+ch] = xp3; \
    s_hx[(bh8+4)*HXP+ch] = xp4; s_hx[(bh8+5)*HXP+ch] = xp5; \
    s_hx[(bh8+6)*HXP+ch] = xp6; s_hx[(bh8+7)*HXP+ch] = xp7; \
    const float* hb = hbuf + (size_t)((S) & 1) * NB * HID + t; \
    _Pragma("unroll") \
    for (int b = 0; b < BPG; b++) s_hx[b*HXP + CIN + t] = hb[(size_t)(bat0+b)*HID]; \
  } while (0)

  PREFX(0);
  STAGE(0);
  __syncthreads();

  for (int s = 0; s < TST; s++) {
    // ---- gate quarter-partials: 2 rows x 8 batches x 96 K, all state in named scalars ----
    float a00 = bias0, a01 = bias0, a02 = bias0, a03 = bias0;
    float a04 = bias0, a05 = bias0, a06 = bias0, a07 = bias0;
    float a10 = bias1, a11 = bias1, a12 = bias1, a13 = bias1;
    float a14 = bias1, a15 = bias1, a16 = bias1, a17 = bias1;
    {
      const float4* wp0 = (const float4*)(s_w + (size_t)r0 * SWP) + kq * 24;
      const float4* wp1 = wp0 + (SWP / 4);
      const float4* hxq = (const float4*)s_hx + bq * 8 * HXQ + kq * 24;
      #pragma unroll
      for (int kk = 0; kk < 24; kk++) {
        const float4 wv0 = wp0[kk];
        const float4 wv1 = wp1[kk];
        const float4 hv0 = hxq[0 * HXQ + kk];
        const float4 hv1 = hxq[1 * HXQ + kk];
        const float4 hv2 = hxq[2 * HXQ + kk];
        const float4 hv3 = hxq[3 * HXQ + kk];
        const float4 hv4 = hxq[4 * HXQ + kk];
        const float4 hv5 = hxq[5 * HXQ + kk];
        const float4 hv6 = hxq[6 * HXQ + kk];
        const float4 hv7 = hxq[7 * HXQ + kk];
        FMA4(a00, wv0, hv0); FMA4(a01, wv0, hv1); FMA4(a02, wv0, hv2); FMA4(a03, wv0, hv3);
        FMA4(a04, wv0, hv4); FMA4(a05, wv0, hv5); FMA4(a06, wv0, hv6); FMA4(a07, wv0, hv7);
        FMA4(a10, wv1, hv0); FMA4(a11, wv1, hv1); FMA4(a12, wv1, hv2); FMA4(a13, wv1, hv3);
        FMA4(a14, wv1, hv4); FMA4(a15, wv1, hv5); FMA4(a16, wv1, hv6); FMA4(a17, wv1, hv7);
      }
    }
    if (s < TST - 1) PREFX(s + 1);   // x loads drain during update/barrier

    {
      float* sp0 = s_part + (size_t)(kq * RPB + r0) * SPD + bq * 8;
      *(float4*)(sp0 + 0) = make_float4(a00, a01, a02, a03);
      *(float4*)(sp0 + 4) = make_float4(a04, a05, a06, a07);
      float* sp1 = sp0 + SPD;
      *(float4*)(sp1 + 0) = make_float4(a10, a11, a12, a13);
      *(float4*)(sp1 + 4) = make_float4(a14, a15, a16, a17);
    }
    __syncthreads();

    // ---- update: thread (j2,b2) reduces its 4 gate rows over the 4 K-quarters ----
    float g0 = 0.f, g1 = 0.f, g2 = 0.f, g3 = 0.f;
    #pragma unroll
    for (int q = 0; q < 4; q++) {
      const float* sp = s_part + (size_t)(q * RPB + j2) * SPD + b2;
      g0 += sp[0 * HPB * SPD];
      g1 += sp[1 * HPB * SPD];
      g2 += sp[2 * HPB * SPD];
      g3 += sp[3 * HPB * SPD];
    }
    c_reg = fmaf(sigm(g1), c_reg, sigm(g0) * tanh_(g2));
    const float h = sigm(g3) * tanh_(c_reg);

    hbuf[(size_t)((s + 1) & 1) * NB * HID + (size_t)(bat0 + b2) * HID + hid0 + j2] = h;
    s_red[b2 * HPB + j2] = (bat0 + b2 < s_lens[s]) ? h : 0.f;
    __syncthreads();

    // masked partial for output row s (wave 1 works while wave 0's t0 handles barrier)
    if (t >= 64 && t < 64 + HPB) {
      const int jl = t - 64;
      float ps = 0.f;
      #pragma unroll
      for (int b = 0; b < BPG; b++) ps += s_red[b * HPB + jl];
      pp[(((size_t)s * GRPS + grp) * MEMB + m) * HPB + jl] = ps;
    }

    if (s == TST - 1) break;

    // ---- 16-block group barrier (ctrs padded to 64B to avoid line sharing) ----
    if (t == 0) {
      __threadfence();   // one flush per block, not 256
      __hip_atomic_fetch_add(ctrs + grp * 16, 1, __ATOMIC_RELEASE, __HIP_MEMORY_SCOPE_AGENT);
      const int target = MEMB * (s + 1);
      while (__hip_atomic_load(ctrs + grp * 16, __ATOMIC_RELAXED, __HIP_MEMORY_SCOPE_AGENT) < target)
        __builtin_amdgcn_s_sleep(2);
      (void)__hip_atomic_load(ctrs + grp * 16, __ATOMIC_ACQUIRE, __HIP_MEMORY_SCOPE_AGENT);
    }
    __syncthreads();
    STAGE(s + 1);
    __syncthreads();
  }
}

// ---------------- masked batch-mean + FC ----------------
__global__ void k_out(const float* __restrict__ pp, const int* __restrict__ lens,
                      const float* __restrict__ fcW, const float* __restrict__ fcb,
                      float* __restrict__ out) {
  const int i = blockIdx.x, t = threadIdx.x;
  __shared__ float s_fc[HID];
  const int cnt = min(lens[i], NB);
  const int m = t >> 4, jl = t & 15;             // hid = t
  float a = 0.f;
  const float* base = pp + ((size_t)i * GRPS * MEMB + m) * HPB + jl;
  #pragma unroll 4
  for (int g = 0; g < GRPS; g++) a += base[(size_t)g * MEMB * HPB];
  s_fc[t] = a / (float)cnt;
  __syncthreads();
  for (int n = t; n < NCLS; n += 256) {
    float acc = fcb[n];
    const float4* w4 = (const float4*)(fcW + (size_t)n * HID);
    #pragma unroll 8
    for (int k4 = 0; k4 < HID / 4; k4++) {
      const float4 wv = w4[k4];
      acc = fmaf(s_fc[4*k4+0], wv.x, acc);
      acc = fmaf(s_fc[4*k4+1], wv.y, acc);
      acc = fmaf(s_fc[4*k4+2], wv.z, acc);
      acc = fmaf(s_fc[4*k4+3], wv.w, acc);
    }
    out[(size_t)i * NCLS + n] = acc;
  }
}

extern "C" void kernel_launch(void* const* d_in, const int* in_sizes, int n_in,
                              void* d_out, int out_size, void* d_ws, size_t ws_size,
                              hipStream_t stream) {
  const float* x    = (const float*)d_in[0];
  const int*   lens = (const int*)  d_in[1];
  const float* Wih  = (const float*)d_in[2];
  const float* Whh  = (const float*)d_in[3];
  const float* bih  = (const float*)d_in[4];
  const float* bhh  = (const float*)d_in[5];
  const float* w1h  = (const float*)d_in[6];
  const float* w2h  = (const float*)d_in[7];
  const float* w1c  = (const float*)d_in[8];
  const float* w2c  = (const float*)d_in[9];
  const float* fcW  = (const float*)d_in[10];
  const float* fcb  = (const float*)d_in[11];
  float* out = (float*)d_out;

  char* ws = (char*)d_ws;
  float* sums = (float*)(ws + WS_SUMS);
  float* hbuf = (float*)(ws + WS_HBUF);
  float* c0   = (float*)(ws + WS_C0);
  int*   ctrs = (int*)  (ws + WS_CTRS);
  float* pp   = (float*)(ws + WS_PP);

  hipMemsetAsync(ctrs, 0, GRPS * 16 * sizeof(int), stream);  // barrier ctrs zeroed every call
  k_segsum<<<NB, 256, 0, stream>>>(x, lens, sums);
  k_init  <<<NB, 256, 0, stream>>>(sums, w1h, w2h, w1c, w2c, hbuf, c0);
  k_lstm  <<<NB, 256, 0, stream>>>(x, lens, Wih, Whh, bih, bhh, c0, hbuf, pp, ctrs);
  k_out   <<<NB, 256, 0, stream>>>(pp, lens, fcW, fcb, out);
}

// Round 9
// 2840.790 us; speedup vs baseline: 17.3580x; 5.5594x over previous
//
#include <hip/hip_runtime.h>
#include <hip/hip_bf16.h>
#include <stdint.h>

#define NB    256   // batch / segments
#define CIN   128   // input channels
#define HID   256   // hidden
#define TST   256   // only first 256 timesteps matter for the output
#define NCLS  400

#define GRPS  16    // batch groups
#define MEMB  16    // blocks per group (hidden-slice members)
#define BPG   16    // batches per group
#define HPB   16    // hidden units per block
#define HXS   392   // s_hxb row stride in SHORTS (384 + 8 pad -> 784B rows, 16B-aligned)
#define SPP   17    // s_part row stride in floats

// ---- workspace layout (bytes) ----
#define WS_SUMS   0u                       // 256*128*4   = 131072
#define WS_HBUF   131072u                  // 2*256*256*4 = 524288  (double-buffered h)
#define WS_C0     655360u                  // 256*256*4   = 262144
#define WS_CTRS   917504u                  // 16 ctrs padded to 64B
#define WS_PP     1048576u                 // 256*16*16*16*4 = 4194304 masked partials

typedef __attribute__((ext_vector_type(8))) short bf16x8;  // 8 bf16 = one MFMA A/B frag
typedef __attribute__((ext_vector_type(4))) float f32x4;   // MFMA accumulator

__device__ __forceinline__ short f2bf(float f) {
  __hip_bfloat16 h = __float2bfloat16(f);
  return *reinterpret_cast<short*>(&h);
}
__device__ __forceinline__ float sigm(float v) { return 1.0f / (1.0f + __expf(-v)); }
__device__ __forceinline__ float tanh_(float v) {
  v = fminf(fmaxf(v, -15.0f), 15.0f);
  const float e = __expf(2.0f * v);
  return (e - 1.0f) / (e + 1.0f);
}

// ---------------- segment sums (the "input_means" that are really sums) ----------------
__global__ void k_segsum(const float* __restrict__ x, const int* __restrict__ lens,
                         float* __restrict__ sums) {
  const int b = blockIdx.x, t = threadIdx.x;
  __shared__ int   s_l[NB];
  __shared__ int   s_red[256];
  __shared__ float s_f[CIN];
  s_l[t] = lens[t];
  __syncthreads();
  int part = 0;
  for (int i = t; i < b; i += 256) part += s_l[i];
  s_red[t] = part; __syncthreads();
  for (int k = 128; k > 0; k >>= 1) { if (t < k) s_red[t] += s_red[t + k]; __syncthreads(); }
  const int off = s_red[0];
  const int len = s_l[b];
  const int c = t & 127, half = t >> 7;
  float a = 0.f;
  for (int r = half; r < len; r += 2) a += x[(size_t)(off + r) * CIN + c];
  if (half) s_f[c] = a;
  __syncthreads();
  if (!half) sums[b * CIN + c] = a + s_f[c];
}

// ---------------- h0 = relu(sums@W1h^T)@W2h^T ; c0 likewise ----------------
__global__ void k_init(const float* __restrict__ sums,
                       const float* __restrict__ w1h, const float* __restrict__ w2h,
                       const float* __restrict__ w1c, const float* __restrict__ w2c,
                       float* __restrict__ hbuf, float* __restrict__ c0) {
  const int b = blockIdx.x, t = threadIdx.x;
  __shared__ float s_in[CIN], s_h[CIN], s_c[CIN];
  if (t < CIN) s_in[t] = sums[b * CIN + t];
  __syncthreads();
  {
    const int j = t & 127;
    const float* w = (t < CIN ? w1h : w1c) + j * CIN;
    float a = 0.f;
    #pragma unroll 8
    for (int k = 0; k < CIN; k++) a += s_in[k] * w[k];
    a = fmaxf(a, 0.f);
    if (t < CIN) s_h[j] = a; else s_c[j] = a;
  }
  __syncthreads();
  float ah = 0.f, ac = 0.f;
  const float* wh = w2h + t * CIN;
  const float* wc = w2c + t * CIN;
  #pragma unroll 8
  for (int k = 0; k < CIN; k++) { ah += s_h[k] * wh[k]; ac += s_c[k] * wc[k]; }
  hbuf[b * HID + t] = ah;   // buffer 0 = h_0
  c0[b * HID + t]   = ac;
}

// ---------------- persistent LSTM recurrence (MFMA) ----------------
// 256 blocks = 16 batch-groups x 16 members. Block = 64 gate-rows x 16 batches, K=384.
// W lives as 12 MFMA A-fragments in VGPRs per thread (48 regs -- loaded ONCE, cannot
// spill-loop). hx staged bf16 in LDS per step; wave kq does K-quarter via 3 B-frags
// x 4 M-tiles = 12 mfma_f32_16x16x32_bf16. K-partials reduced via LDS as before.
// R1-R8 lesson: any fp32 VALU-GEMM formulation here either spills (10-120 GB scratch)
// or is LDS-pipe-bound (~1ms floor). MFMA removes both.
__launch_bounds__(256, 1)
__global__ void k_lstm(const float* __restrict__ x, const int* __restrict__ lens,
                       const float* __restrict__ Wih, const float* __restrict__ Whh,
                       const float* __restrict__ bih, const float* __restrict__ bhh,
                       const float* __restrict__ c0,
                       float* __restrict__ hbuf, float* __restrict__ pp,
                       int* __restrict__ ctrs) {
  const int p    = blockIdx.x;
  const int m    = p >> 4;            // member 0..15 (hidden slice)
  const int grp  = p & 15;            // batch group 0..15
  const int bat0 = grp * BPG;
  const int hid0 = m * HPB;

  const int t   = threadIdx.x;
  const int kq  = t >> 6;             // K-quarter == wave id
  const int l15 = t & 15;             // MFMA: A-row-in-tile / B-col(batch) / C-col
  const int hi  = (t >> 4) & 3;       // MFMA: k-subchunk / C row-group

  const int j2 = t & 15, b2 = t >> 4;           // update role: (hid j2, batch b2)
  const int ch = t & 127, bh8 = (t >> 7) * 8;   // x staging: channel + batch-octet

  __shared__ __align__(16) short s_hxb[BPG * HXS];   // bf16 [16 b][384k +pad] = 12.5 KB
  __shared__ float s_part[4 * 64 * SPP];             // 17.4 KB K-quarter partials
  __shared__ float s_red[256];
  __shared__ int   s_lens[NB];
  __shared__ int   s_off[BPG], s_len[BPG];

  s_lens[t] = lens[t];
  __syncthreads();
  if (t < BPG) {
    int off = 0;
    for (int k = 0; k < bat0 + t; k++) off += s_lens[k];
    s_off[t] = off;
    s_len[t] = s_lens[bat0 + t];
  }
  __syncthreads();   // (R8 latent race fixed: PREFX reads s_len)

  // ---- persistent W as MFMA A-fragments: frag(mt,kc), row=16mt+(lane&15),
  //      k = kq*96 + kc*32 + (lane>>4)*8 + e  (A and B share this k-map) ----
  #define LOADA(AV, MT, KC) do {                                                   \
    const int grow_ = (MT) * HID + hid0 + l15;                                     \
    const int k0_   = kq * 96 + (KC) * 32 + hi * 8;                                \
    const float* src_ = (k0_ < CIN) ? (Wih + (size_t)grow_ * CIN + k0_)            \
                                    : (Whh + (size_t)grow_ * HID + (k0_ - CIN));   \
    const float4 f0_ = *(const float4*)(src_);                                     \
    const float4 f1_ = *(const float4*)(src_ + 4);                                 \
    AV[0]=f2bf(f0_.x); AV[1]=f2bf(f0_.y); AV[2]=f2bf(f0_.z); AV[3]=f2bf(f0_.w);    \
    AV[4]=f2bf(f1_.x); AV[5]=f2bf(f1_.y); AV[6]=f2bf(f1_.z); AV[7]=f2bf(f1_.w);    \
  } while (0)
  bf16x8 a00, a01, a02, a10, a11, a12, a20, a21, a22, a30, a31, a32;
  LOADA(a00,0,0); LOADA(a01,0,1); LOADA(a02,0,2);
  LOADA(a10,1,0); LOADA(a11,1,1); LOADA(a12,1,2);
  LOADA(a20,2,0); LOADA(a21,2,1); LOADA(a22,2,2);
  LOADA(a30,3,0); LOADA(a31,3,1); LOADA(a32,3,2);

  // update-role biases (gate order i,f,g,o)
  const float bias0 = bih[0*HID + hid0 + j2] + bhh[0*HID + hid0 + j2];
  const float bias1 = bih[1*HID + hid0 + j2] + bhh[1*HID + hid0 + j2];
  const float bias2 = bih[2*HID + hid0 + j2] + bhh[2*HID + hid0 + j2];
  const float bias3 = bih[3*HID + hid0 + j2] + bhh[3*HID + hid0 + j2];

  float c_reg = c0[(size_t)(bat0 + b2) * HID + hid0 + j2];

  float xp0, xp1, xp2, xp3, xp4, xp5, xp6, xp7;
  #define PREFX(S) do { \
    xp0 = ((S) < s_len[bh8+0]) ? x[(size_t)(s_off[bh8+0]+(S))*CIN+ch] : 0.f; \
    xp1 = ((S) < s_len[bh8+1]) ? x[(size_t)(s_off[bh8+1]+(S))*CIN+ch] : 0.f; \
    xp2 = ((S) < s_len[bh8+2]) ? x[(size_t)(s_off[bh8+2]+(S))*CIN+ch] : 0.f; \
    xp3 = ((S) < s_len[bh8+3]) ? x[(size_t)(s_off[bh8+3]+(S))*CIN+ch] : 0.f; \
    xp4 = ((S) < s_len[bh8+4]) ? x[(size_t)(s_off[bh8+4]+(S))*CIN+ch] : 0.f; \
    xp5 = ((S) < s_len[bh8+5]) ? x[(size_t)(s_off[bh8+5]+(S))*CIN+ch] : 0.f; \
    xp6 = ((S) < s_len[bh8+6]) ? x[(size_t)(s_off[bh8+6]+(S))*CIN+ch] : 0.f; \
    xp7 = ((S) < s_len[bh8+7]) ? x[(size_t)(s_off[bh8+7]+(S))*CIN+ch] : 0.f; \
  } while (0)
  #define STAGE(S) do { \
    s_hxb[(bh8+0)*HXS+ch]=f2bf(xp0); s_hxb[(bh8+1)*HXS+ch]=f2bf(xp1); \
    s_hxb[(bh8+2)*HXS+ch]=f2bf(xp2); s_hxb[(bh8+3)*HXS+ch]=f2bf(xp3); \
    s_hxb[(bh8+4)*HXS+ch]=f2bf(xp4); s_hxb[(bh8+5)*HXS+ch]=f2bf(xp5); \
    s_hxb[(bh8+6)*HXS+ch]=f2bf(xp6); s_hxb[(bh8+7)*HXS+ch]=f2bf(xp7); \
    const float* hb_ = hbuf + (size_t)((S) & 1) * NB * HID + t; \
    _Pragma("unroll") \
    for (int b = 0; b < BPG; b++) \
      s_hxb[b*HXS + CIN + t] = f2bf(hb_[(size_t)(bat0 + b) * HID]); \
  } while (0)

  PREFX(0);
  STAGE(0);
  __syncthreads();

  for (int s = 0; s < TST; s++) {
    // ---- gate K-quarter partials via MFMA: 3 B-frags x 4 M-tiles ----
    f32x4 d0 = {0.f,0.f,0.f,0.f}, d1 = {0.f,0.f,0.f,0.f};
    f32x4 d2 = {0.f,0.f,0.f,0.f}, d3 = {0.f,0.f,0.f,0.f};
    {
      const short* hxb = s_hxb + l15 * HXS + kq * 96 + hi * 8;
      bf16x8 bv;
      bv = *(const bf16x8*)(hxb + 0);
      d0 = __builtin_amdgcn_mfma_f32_16x16x32_bf16(a00, bv, d0, 0, 0, 0);
      d1 = __builtin_amdgcn_mfma_f32_16x16x32_bf16(a10, bv, d1, 0, 0, 0);
      d2 = __builtin_amdgcn_mfma_f32_16x16x32_bf16(a20, bv, d2, 0, 0, 0);
      d3 = __builtin_amdgcn_mfma_f32_16x16x32_bf16(a30, bv, d3, 0, 0, 0);
      bv = *(const bf16x8*)(hxb + 32);
      d0 = __builtin_amdgcn_mfma_f32_16x16x32_bf16(a01, bv, d0, 0, 0, 0);
      d1 = __builtin_amdgcn_mfma_f32_16x16x32_bf16(a11, bv, d1, 0, 0, 0);
      d2 = __builtin_amdgcn_mfma_f32_16x16x32_bf16(a21, bv, d2, 0, 0, 0);
      d3 = __builtin_amdgcn_mfma_f32_16x16x32_bf16(a31, bv, d3, 0, 0, 0);
      bv = *(const bf16x8*)(hxb + 64);
      d0 = __builtin_amdgcn_mfma_f32_16x16x32_bf16(a02, bv, d0, 0, 0, 0);
      d1 = __builtin_amdgcn_mfma_f32_16x16x32_bf16(a12, bv, d1, 0, 0, 0);
      d2 = __builtin_amdgcn_mfma_f32_16x16x32_bf16(a22, bv, d2, 0, 0, 0);
      d3 = __builtin_amdgcn_mfma_f32_16x16x32_bf16(a32, bv, d3, 0, 0, 0);
    }
    if (s < TST - 1) PREFX(s + 1);   // x loads drain during update/barrier

    // C layout (m89-verified): col = lane&15, row = 16*mt + (lane>>4)*4 + reg
    {
      const int rb = kq * 64 + hi * 4;
      float* spc = s_part + (size_t)rb * SPP + l15;
      spc[(0*16 + 0)*SPP] = d0[0]; spc[(0*16 + 1)*SPP] = d0[1];
      spc[(0*16 + 2)*SPP] = d0[2]; spc[(0*16 + 3)*SPP] = d0[3];
      spc[(1*16 + 0)*SPP] = d1[0]; spc[(1*16 + 1)*SPP] = d1[1];
      spc[(1*16 + 2)*SPP] = d1[2]; spc[(1*16 + 3)*SPP] = d1[3];
      spc[(2*16 + 0)*SPP] = d2[0]; spc[(2*16 + 1)*SPP] = d2[1];
      spc[(2*16 + 2)*SPP] = d2[2]; spc[(2*16 + 3)*SPP] = d2[3];
      spc[(3*16 + 0)*SPP] = d3[0]; spc[(3*16 + 1)*SPP] = d3[1];
      spc[(3*16 + 2)*SPP] = d3[2]; spc[(3*16 + 3)*SPP] = d3[3];
    }
    __syncthreads();

    // ---- update: thread (j2,b2) sums 4 K-quarters for its 4 gate rows ----
    float g0 = bias0, g1 = bias1, g2 = bias2, g3 = bias3;
    #pragma unroll
    for (int q = 0; q < 4; q++) {
      const float* spq = s_part + (size_t)(q * 64 + j2) * SPP + b2;
      g0 += spq[ 0 * SPP];
      g1 += spq[16 * SPP];
      g2 += spq[32 * SPP];
      g3 += spq[48 * SPP];
    }
    c_reg = fmaf(sigm(g1), c_reg, sigm(g0) * tanh_(g2));
    const float h = sigm(g3) * tanh_(c_reg);

    hbuf[(size_t)((s + 1) & 1) * NB * HID + (size_t)(bat0 + b2) * HID + hid0 + j2] = h;
    s_red[b2 * HPB + j2] = (bat0 + b2 < s_lens[s]) ? h : 0.f;
    __syncthreads();

    // masked partial for output row s (wave 1 works while wave 0's t0 runs the barrier)
    if (t >= 64 && t < 64 + HPB) {
      const int jl = t - 64;
      float ps = 0.f;
      #pragma unroll
      for (int b = 0; b < BPG; b++) ps += s_red[b * HPB + jl];
      pp[(((size_t)s * GRPS + grp) * MEMB + m) * HPB + jl] = ps;
    }

    if (s == TST - 1) break;

    // ---- 16-block group barrier (release arrive, relaxed spin + sleep, one acquire) ----
    if (t == 0) {
      __threadfence();
      __hip_atomic_fetch_add(ctrs + grp * 16, 1, __ATOMIC_RELEASE, __HIP_MEMORY_SCOPE_AGENT);
      const int target = MEMB * (s + 1);
      while (__hip_atomic_load(ctrs + grp * 16, __ATOMIC_RELAXED, __HIP_MEMORY_SCOPE_AGENT) < target)
        __builtin_amdgcn_s_sleep(2);
      (void)__hip_atomic_load(ctrs + grp * 16, __ATOMIC_ACQUIRE, __HIP_MEMORY_SCOPE_AGENT);
    }
    __syncthreads();
    STAGE(s + 1);
    __syncthreads();
  }
}

// ---------------- masked batch-mean + FC ----------------
__global__ void k_out(const float* __restrict__ pp, const int* __restrict__ lens,
                      const float* __restrict__ fcW, const float* __restrict__ fcb,
                      float* __restrict__ out) {
  const int i = blockIdx.x, t = threadIdx.x;
  __shared__ float s_fc[HID];
  const int cnt = min(lens[i], NB);
  const int m = t >> 4, jl = t & 15;             // hid = t
  float a = 0.f;
  const float* base = pp + ((size_t)i * GRPS * MEMB + m) * HPB + jl;
  #pragma unroll 4
  for (int g = 0; g < GRPS; g++) a += base[(size_t)g * MEMB * HPB];
  s_fc[t] = a / (float)cnt;
  __syncthreads();
  for (int n = t; n < NCLS; n += 256) {
    float acc = fcb[n];
    const float4* w4 = (const float4*)(fcW + (size_t)n * HID);
    #pragma unroll 8
    for (int k4 = 0; k4 < HID / 4; k4++) {
      const float4 wv = w4[k4];
      acc = fmaf(s_fc[4*k4+0], wv.x, acc);
      acc = fmaf(s_fc[4*k4+1], wv.y, acc);
      acc = fmaf(s_fc[4*k4+2], wv.z, acc);
      acc = fmaf(s_fc[4*k4+3], wv.w, acc);
    }
    out[(size_t)i * NCLS + n] = acc;
  }
}

extern "C" void kernel_launch(void* const* d_in, const int* in_sizes, int n_in,
                              void* d_out, int out_size, void* d_ws, size_t ws_size,
                              hipStream_t stream) {
  const float* x    = (const float*)d_in[0];
  const int*   lens = (const int*)  d_in[1];
  const float* Wih  = (const float*)d_in[2];
  const float* Whh  = (const float*)d_in[3];
  const float* bih  = (const float*)d_in[4];
  const float* bhh  = (const float*)d_in[5];
  const float* w1h  = (const float*)d_in[6];
  const float* w2h  = (const float*)d_in[7];
  const float* w1c  = (const float*)d_in[8];
  const float* w2c  = (const float*)d_in[9];
  const float* fcW  = (const float*)d_in[10];
  const float* fcb  = (const float*)d_in[11];
  float* out = (float*)d_out;

  char* ws = (char*)d_ws;
  float* sums = (float*)(ws + WS_SUMS);
  float* hbuf = (float*)(ws + WS_HBUF);
  float* c0   = (float*)(ws + WS_C0);
  int*   ctrs = (int*)  (ws + WS_CTRS);
  float* pp   = (float*)(ws + WS_PP);

  hipMemsetAsync(ctrs, 0, GRPS * 16 * sizeof(int), stream);  // barrier ctrs zeroed every call
  k_segsum<<<NB, 256, 0, stream>>>(x, lens, sums);
  k_init  <<<NB, 256, 0, stream>>>(sums, w1h, w2h, w1c, w2c, hbuf, c0);
  k_lstm  <<<NB, 256, 0, stream>>>(x, lens, Wih, Whh, bih, bhh, c0, hbuf, pp, ctrs);
  k_out   <<<NB, 256, 0, stream>>>(pp, lens, fcW, fcb, out);
}

// Round 10
// 1227.196 us; speedup vs baseline: 40.1814x; 2.3149x over previous
//
#include <hip/hip_runtime.h>
#include <hip/hip_bf16.h>
#include <stdint.h>

#define NB    256   // batch / segments
#define CIN   128   // input channels
#define HID   256   // hidden
#define TST   256   // only first 256 timesteps matter for the output
#define NCLS  400

#define GRPS  16    // batch groups
#define MEMB  4     // blocks per group (hidden-slice members)
#define BPG   16    // batches per group
#define HPB   64    // hidden units per block
#define RPB   256   // gate rows per block (4 gates x 64 hid)
#define HXS   392   // s_hxb row stride in SHORTS (384 + 8 pad)
#define SPP   17    // s_part row stride in floats

// ---- workspace layout (bytes) ----
#define WS_SUMS   0u                       // 256*128*4   = 131072
#define WS_HBUF   131072u                  // 2*256*256*4 = 524288  (double-buffered h)
#define WS_C0     655360u                  // 256*256*4   = 262144
#define WS_CTRS   917504u                  // 16 ctrs padded to 64B
#define WS_PP     1048576u                 // 256*16*4*64*4 = 4194304 masked partials

typedef __attribute__((ext_vector_type(8))) short bf16x8;  // 8 bf16 = one MFMA A/B frag
typedef __attribute__((ext_vector_type(4))) float f32x4;   // MFMA accumulator

__device__ __forceinline__ short f2bf(float f) {
  __hip_bfloat16 h = __float2bfloat16(f);
  return *reinterpret_cast<short*>(&h);
}
__device__ __forceinline__ float sigm(float v) { return 1.0f / (1.0f + __expf(-v)); }
__device__ __forceinline__ float tanh_(float v) {
  v = fminf(fmaxf(v, -15.0f), 15.0f);
  const float e = __expf(2.0f * v);
  return (e - 1.0f) / (e + 1.0f);
}

// ---------------- segment sums (the "input_means" that are really sums) ----------------
__global__ void k_segsum(const float* __restrict__ x, const int* __restrict__ lens,
                         float* __restrict__ sums) {
  const int b = blockIdx.x, t = threadIdx.x;
  __shared__ int   s_l[NB];
  __shared__ int   s_red[256];
  __shared__ float s_f[CIN];
  s_l[t] = lens[t];
  __syncthreads();
  int part = 0;
  for (int i = t; i < b; i += 256) part += s_l[i];
  s_red[t] = part; __syncthreads();
  for (int k = 128; k > 0; k >>= 1) { if (t < k) s_red[t] += s_red[t + k]; __syncthreads(); }
  const int off = s_red[0];
  const int len = s_l[b];
  const int c = t & 127, half = t >> 7;
  float a = 0.f;
  for (int r = half; r < len; r += 2) a += x[(size_t)(off + r) * CIN + c];
  if (half) s_f[c] = a;
  __syncthreads();
  if (!half) sums[b * CIN + c] = a + s_f[c];
}

// ---------------- h0 = relu(sums@W1h^T)@W2h^T ; c0 likewise ----------------
__global__ void k_init(const float* __restrict__ sums,
                       const float* __restrict__ w1h, const float* __restrict__ w2h,
                       const float* __restrict__ w1c, const float* __restrict__ w2c,
                       float* __restrict__ hbuf, float* __restrict__ c0) {
  const int b = blockIdx.x, t = threadIdx.x;
  __shared__ float s_in[CIN], s_h[CIN], s_c[CIN];
  if (t < CIN) s_in[t] = sums[b * CIN + t];
  __syncthreads();
  {
    const int j = t & 127;
    const float* w = (t < CIN ? w1h : w1c) + j * CIN;
    float a = 0.f;
    #pragma unroll 8
    for (int k = 0; k < CIN; k++) a += s_in[k] * w[k];
    a = fmaxf(a, 0.f);
    if (t < CIN) s_h[j] = a; else s_c[j] = a;
  }
  __syncthreads();
  float ah = 0.f, ac = 0.f;
  const float* wh = w2h + t * CIN;
  const float* wc = w2c + t * CIN;
  #pragma unroll 8
  for (int k = 0; k < CIN; k++) { ah += s_h[k] * wh[k]; ac += s_c[k] * wc[k]; }
  hbuf[b * HID + t] = ah;   // buffer 0 = h_0
  c0[b * HID + t]   = ac;
}

// ---------------- persistent LSTM recurrence (MFMA, 64 big blocks) ----------------
// 64 blocks x 1024 threads = 16 groups (16 batches) x 4 members (64 hid = 256 rows).
// R9 was correct but sync-bound: 10.9us/step with 256 blocks each doing an
// agent-scope wbl2+inv per step. This round quarters the fence count (64 blocks)
// and the barrier fan-in (4 arrivals); 16 waves = 4 M-quadrants x 4 K-quarters,
// per-thread MFMA structure identical to R9 (12 A-frags, 48 VGPRs, fits 128 cap).
__launch_bounds__(1024, 1)
__global__ void k_lstm(const float* __restrict__ x, const int* __restrict__ lens,
                       const float* __restrict__ Wih, const float* __restrict__ Whh,
                       const float* __restrict__ bih, const float* __restrict__ bhh,
                       const float* __restrict__ c0,
                       float* __restrict__ hbuf, float* __restrict__ pp,
                       int* __restrict__ ctrs) {
  const int p    = blockIdx.x;        // 0..63
  const int m    = p >> 4;            // member 0..3 (hidden slice of 64)
  const int grp  = p & 15;            // batch group 0..15 (members at stride 16 -> same XCD)
  const int bat0 = grp * BPG;
  const int hid0 = m * HPB;

  const int t   = threadIdx.x;        // 0..1023
  const int w   = t >> 6;             // wave 0..15
  const int kq  = w & 3;              // K-quarter
  const int mq  = w >> 2;             // M-quadrant (4 M-tiles each)
  const int l15 = t & 15;             // MFMA lane col
  const int hi  = (t >> 4) & 3;       // MFMA lane row-group

  const int j2 = t & 63, b2 = t >> 6;           // update role: (hid j2, batch b2) 64x16
  const int ch = t & 127, bp2 = (t >> 7) * 2;   // x staging: channel + batch-pair

  __shared__ __align__(16) short s_hxb[BPG * HXS];   // bf16 [16 b][384k+pad] = 12.5 KB
  __shared__ float s_part[4 * RPB * SPP];            // 69.6 KB K-quarter partials
  __shared__ float s_red[1024];
  __shared__ int   s_lens[NB];
  __shared__ int   s_off[BPG], s_len[BPG];

  if (t < NB) s_lens[t] = lens[t];
  __syncthreads();
  if (t < BPG) {
    int off = 0;
    for (int k = 0; k < bat0 + t; k++) off += s_lens[k];
    s_off[t] = off;
    s_len[t] = s_lens[bat0 + t];
  }
  __syncthreads();

  // ---- persistent W as MFMA A-fragments ----
  // local row lr = mt*16 + l15  (mt = mq*4 + i); gate = lr>>6, hidLocal = lr&63
  // k = kq*96 + kc*32 + hi*8 + e   (A and B share this k-map, so any k-permute cancels)
  #define LOADA(AV, MT, KC) do {                                                   \
    const int lr_   = (MT) * 16 + l15;                                             \
    const int grow_ = (lr_ >> 6) * HID + hid0 + (lr_ & 63);                        \
    const int k0_   = kq * 96 + (KC) * 32 + hi * 8;                                \
    const float* src_ = (k0_ < CIN) ? (Wih + (size_t)grow_ * CIN + k0_)            \
                                    : (Whh + (size_t)grow_ * HID + (k0_ - CIN));   \
    const float4 f0_ = *(const float4*)(src_);                                     \
    const float4 f1_ = *(const float4*)(src_ + 4);                                 \
    AV[0]=f2bf(f0_.x); AV[1]=f2bf(f0_.y); AV[2]=f2bf(f0_.z); AV[3]=f2bf(f0_.w);    \
    AV[4]=f2bf(f1_.x); AV[5]=f2bf(f1_.y); AV[6]=f2bf(f1_.z); AV[7]=f2bf(f1_.w);    \
  } while (0)
  bf16x8 a00, a01, a02, a10, a11, a12, a20, a21, a22, a30, a31, a32;
  LOADA(a00, mq*4+0, 0); LOADA(a01, mq*4+0, 1); LOADA(a02, mq*4+0, 2);
  LOADA(a10, mq*4+1, 0); LOADA(a11, mq*4+1, 1); LOADA(a12, mq*4+1, 2);
  LOADA(a20, mq*4+2, 0); LOADA(a21, mq*4+2, 1); LOADA(a22, mq*4+2, 2);
  LOADA(a30, mq*4+3, 0); LOADA(a31, mq*4+3, 1); LOADA(a32, mq*4+3, 2);

  // update-role biases (gate order i,f,g,o)
  const float bias0 = bih[0*HID + hid0 + j2] + bhh[0*HID + hid0 + j2];
  const float bias1 = bih[1*HID + hid0 + j2] + bhh[1*HID + hid0 + j2];
  const float bias2 = bih[2*HID + hid0 + j2] + bhh[2*HID + hid0 + j2];
  const float bias3 = bih[3*HID + hid0 + j2] + bhh[3*HID + hid0 + j2];

  float c_reg = c0[(size_t)(bat0 + b2) * HID + hid0 + j2];

  float xp0, xp1;
  #define PREFX(S) do { \
    xp0 = ((S) < s_len[bp2+0]) ? x[(size_t)(s_off[bp2+0]+(S))*CIN+ch] : 0.f; \
    xp1 = ((S) < s_len[bp2+1]) ? x[(size_t)(s_off[bp2+1]+(S))*CIN+ch] : 0.f; \
  } while (0)
  // h staging: thread = (hidden k = t&255, batch-quad bq = t>>8)
  #define STAGE(S) do { \
    s_hxb[(bp2+0)*HXS+ch] = f2bf(xp0); \
    s_hxb[(bp2+1)*HXS+ch] = f2bf(xp1); \
    const int k_  = t & 255, bq_ = t >> 8; \
    const float* hb_ = hbuf + (size_t)((S) & 1) * NB * HID + k_; \
    _Pragma("unroll") \
    for (int i = 0; i < 4; i++) { \
      const int b_ = bq_ * 4 + i; \
      s_hxb[b_*HXS + CIN + k_] = f2bf(hb_[(size_t)(bat0 + b_) * HID]); \
    } \
  } while (0)

  PREFX(0);
  STAGE(0);
  __syncthreads();

  for (int s = 0; s < TST; s++) {
    // ---- gate K-quarter partials via MFMA: 3 B-frags x 4 M-tiles per wave ----
    f32x4 d0 = {0.f,0.f,0.f,0.f}, d1 = {0.f,0.f,0.f,0.f};
    f32x4 d2 = {0.f,0.f,0.f,0.f}, d3 = {0.f,0.f,0.f,0.f};
    {
      const short* hxb = s_hxb + l15 * HXS + kq * 96 + hi * 8;
      bf16x8 bv;
      bv = *(const bf16x8*)(hxb + 0);
      d0 = __builtin_amdgcn_mfma_f32_16x16x32_bf16(a00, bv, d0, 0, 0, 0);
      d1 = __builtin_amdgcn_mfma_f32_16x16x32_bf16(a10, bv, d1, 0, 0, 0);
      d2 = __builtin_amdgcn_mfma_f32_16x16x32_bf16(a20, bv, d2, 0, 0, 0);
      d3 = __builtin_amdgcn_mfma_f32_16x16x32_bf16(a30, bv, d3, 0, 0, 0);
      bv = *(const bf16x8*)(hxb + 32);
      d0 = __builtin_amdgcn_mfma_f32_16x16x32_bf16(a01, bv, d0, 0, 0, 0);
      d1 = __builtin_amdgcn_mfma_f32_16x16x32_bf16(a11, bv, d1, 0, 0, 0);
      d2 = __builtin_amdgcn_mfma_f32_16x16x32_bf16(a21, bv, d2, 0, 0, 0);
      d3 = __builtin_amdgcn_mfma_f32_16x16x32_bf16(a31, bv, d3, 0, 0, 0);
      bv = *(const bf16x8*)(hxb + 64);
      d0 = __builtin_amdgcn_mfma_f32_16x16x32_bf16(a02, bv, d0, 0, 0, 0);
      d1 = __builtin_amdgcn_mfma_f32_16x16x32_bf16(a12, bv, d1, 0, 0, 0);
      d2 = __builtin_amdgcn_mfma_f32_16x16x32_bf16(a22, bv, d2, 0, 0, 0);
      d3 = __builtin_amdgcn_mfma_f32_16x16x32_bf16(a32, bv, d3, 0, 0, 0);
    }
    if (s < TST - 1) PREFX(s + 1);   // x loads drain during update/barrier

    // C layout (m89-verified): col = lane&15, local row = 16*mt + hi*4 + reg
    {
      float* spc = s_part + (size_t)(kq * RPB + mq * 64 + hi * 4) * SPP + l15;
      spc[(0*16 + 0)*SPP] = d0[0]; spc[(0*16 + 1)*SPP] = d0[1];
      spc[(0*16 + 2)*SPP] = d0[2]; spc[(0*16 + 3)*SPP] = d0[3];
      spc[(1*16 + 0)*SPP] = d1[0]; spc[(1*16 + 1)*SPP] = d1[1];
      spc[(1*16 + 2)*SPP] = d1[2]; spc[(1*16 + 3)*SPP] = d1[3];
      spc[(2*16 + 0)*SPP] = d2[0]; spc[(2*16 + 1)*SPP] = d2[1];
      spc[(2*16 + 2)*SPP] = d2[2]; spc[(2*16 + 3)*SPP] = d2[3];
      spc[(3*16 + 0)*SPP] = d3[0]; spc[(3*16 + 1)*SPP] = d3[1];
      spc[(3*16 + 2)*SPP] = d3[2]; spc[(3*16 + 3)*SPP] = d3[3];
    }
    __syncthreads();

    // ---- update: thread (j2,b2) sums 4 K-quarters for its 4 gate rows ----
    float g0 = bias0, g1 = bias1, g2 = bias2, g3 = bias3;
    #pragma unroll
    for (int q = 0; q < 4; q++) {
      const float* spq = s_part + (size_t)(q * RPB + j2) * SPP + b2;
      g0 += spq[(0 * 64) * SPP];
      g1 += spq[(1 * 64) * SPP];
      g2 += spq[(2 * 64) * SPP];
      g3 += spq[(3 * 64) * SPP];
    }
    c_reg = fmaf(sigm(g1), c_reg, sigm(g0) * tanh_(g2));
    const float h = sigm(g3) * tanh_(c_reg);

    hbuf[(size_t)((s + 1) & 1) * NB * HID + (size_t)(bat0 + b2) * HID + hid0 + j2] = h;
    s_red[b2 * HPB + j2] = (bat0 + b2 < s_lens[s]) ? h : 0.f;
    __syncthreads();

    // masked partial for output row s (runs while t0 handles the barrier)
    if (t >= 64 && t < 64 + HPB) {
      const int jl = t - 64;
      float ps = 0.f;
      #pragma unroll
      for (int b = 0; b < BPG; b++) ps += s_red[b * HPB + jl];
      pp[(((size_t)s * GRPS + grp) * MEMB + m) * HPB + jl] = ps;
    }

    if (s == TST - 1) break;

    // ---- 4-block group barrier (release arrive, relaxed spin + sleep, one acquire) ----
    if (t == 0) {
      __threadfence();
      __hip_atomic_fetch_add(ctrs + grp * 16, 1, __ATOMIC_RELEASE, __HIP_MEMORY_SCOPE_AGENT);
      const int target = MEMB * (s + 1);
      while (__hip_atomic_load(ctrs + grp * 16, __ATOMIC_RELAXED, __HIP_MEMORY_SCOPE_AGENT) < target)
        __builtin_amdgcn_s_sleep(1);
      (void)__hip_atomic_load(ctrs + grp * 16, __ATOMIC_ACQUIRE, __HIP_MEMORY_SCOPE_AGENT);
    }
    __syncthreads();
    STAGE(s + 1);
    __syncthreads();
  }
}

// ---------------- masked batch-mean + FC ----------------
__global__ void k_out(const float* __restrict__ pp, const int* __restrict__ lens,
                      const float* __restrict__ fcW, const float* __restrict__ fcb,
                      float* __restrict__ out) {
  const int i = blockIdx.x, t = threadIdx.x;
  __shared__ float s_fc[HID];
  const int cnt = min(lens[i], NB);
  const int m = t >> 6, jl = t & 63;             // hid = t
  float a = 0.f;
  const float* base = pp + ((size_t)i * GRPS * MEMB + m) * HPB + jl;
  #pragma unroll 4
  for (int g = 0; g < GRPS; g++) a += base[(size_t)g * MEMB * HPB];
  s_fc[t] = a / (float)cnt;
  __syncthreads();
  for (int n = t; n < NCLS; n += 256) {
    float acc = fcb[n];
    const float4* w4 = (const float4*)(fcW + (size_t)n * HID);
    #pragma unroll 8
    for (int k4 = 0; k4 < HID / 4; k4++) {
      const float4 wv = w4[k4];
      acc = fmaf(s_fc[4*k4+0], wv.x, acc);
      acc = fmaf(s_fc[4*k4+1], wv.y, acc);
      acc = fmaf(s_fc[4*k4+2], wv.z, acc);
      acc = fmaf(s_fc[4*k4+3], wv.w, acc);
    }
    out[(size_t)i * NCLS + n] = acc;
  }
}

extern "C" void kernel_launch(void* const* d_in, const int* in_sizes, int n_in,
                              void* d_out, int out_size, void* d_ws, size_t ws_size,
                              hipStream_t stream) {
  const float* x    = (const float*)d_in[0];
  const int*   lens = (const int*)  d_in[1];
  const float* Wih  = (const float*)d_in[2];
  const float* Whh  = (const float*)d_in[3];
  const float* bih  = (const float*)d_in[4];
  const float* bhh  = (const float*)d_in[5];
  const float* w1h  = (const float*)d_in[6];
  const float* w2h  = (const float*)d_in[7];
  const float* w1c  = (const float*)d_in[8];
  const float* w2c  = (const float*)d_in[9];
  const float* fcW  = (const float*)d_in[10];
  const float* fcb  = (const float*)d_in[11];
  float* out = (float*)d_out;

  char* ws = (char*)d_ws;
  float* sums = (float*)(ws + WS_SUMS);
  float* hbuf = (float*)(ws + WS_HBUF);
  float* c0   = (float*)(ws + WS_C0);
  int*   ctrs = (int*)  (ws + WS_CTRS);
  float* pp   = (float*)(ws + WS_PP);

  hipMemsetAsync(ctrs, 0, GRPS * 16 * sizeof(int), stream);  // barrier ctrs zeroed every call
  k_segsum<<<NB, 256, 0, stream>>>(x, lens, sums);
  k_init  <<<NB, 256, 0, stream>>>(sums, w1h, w2h, w1c, w2c, hbuf, c0);
  k_lstm  <<<GRPS * MEMB, 1024, 0, stream>>>(x, lens, Wih, Whh, bih, bhh, c0, hbuf, pp, ctrs);
  k_out   <<<NB, 256, 0, stream>>>(pp, lens, fcW, fcb, out);
}

// Round 11
// 877.257 us; speedup vs baseline: 56.2098x; 1.3989x over previous
//
#include <hip/hip_runtime.h>
#include <hip/hip_bf16.h>
#include <stdint.h>

#define NB    256   // batch / segments
#define CIN   128   // input channels
#define HID   256   // hidden
#define TST   256   // only first 256 timesteps matter for the output
#define NCLS  400

#define GRPS  16    // batch groups
#define MEMB  4     // blocks per group (hidden-slice members)
#define BPG   16    // batches per group
#define HPB   64    // hidden units per block
#define RPB   256   // gate rows per block (4 gates x 64 hid)
#define HXS   392   // s_hxb row stride in SHORTS (384 + 8 pad)
#define SPP   17    // s_part row stride in floats

// ---- workspace layout (bytes) ----
#define WS_SUMS   0u                       // 256*128*4   = 131072
#define WS_HEX    131072u                  // u64[2][256][64] = 262144 packed-bf16 h exchange
#define WS_C0     655360u                  // 256*256*4   = 262144
#define WS_CTRS   917504u                  // 16 ctrs padded to 64B
#define WS_PP     1048576u                 // 256*16*4*64*4 = 4194304 masked partials

typedef __attribute__((ext_vector_type(8))) short bf16x8;  // 8 bf16 = one MFMA A/B frag
typedef __attribute__((ext_vector_type(4))) float f32x4;   // MFMA accumulator
typedef unsigned long long u64;

__device__ __forceinline__ short f2bf(float f) {
  __hip_bfloat16 h = __float2bfloat16(f);
  return *reinterpret_cast<short*>(&h);
}
__device__ __forceinline__ float sigm(float v) { return 1.0f / (1.0f + __expf(-v)); }
__device__ __forceinline__ float tanh_(float v) {
  v = fminf(fmaxf(v, -15.0f), 15.0f);
  const float e = __expf(2.0f * v);
  return (e - 1.0f) / (e + 1.0f);
}

// ---------------- segment sums (the "input_means" that are really sums) ----------------
__global__ void k_segsum(const float* __restrict__ x, const int* __restrict__ lens,
                         float* __restrict__ sums) {
  const int b = blockIdx.x, t = threadIdx.x;
  __shared__ int   s_l[NB];
  __shared__ int   s_red[256];
  __shared__ float s_f[CIN];
  s_l[t] = lens[t];
  __syncthreads();
  int part = 0;
  for (int i = t; i < b; i += 256) part += s_l[i];
  s_red[t] = part; __syncthreads();
  for (int k = 128; k > 0; k >>= 1) { if (t < k) s_red[t] += s_red[t + k]; __syncthreads(); }
  const int off = s_red[0];
  const int len = s_l[b];
  const int c = t & 127, half = t >> 7;
  float a = 0.f;
  for (int r = half; r < len; r += 2) a += x[(size_t)(off + r) * CIN + c];
  if (half) s_f[c] = a;
  __syncthreads();
  if (!half) sums[b * CIN + c] = a + s_f[c];
}

// ---------------- h0 = relu(sums@W1h^T)@W2h^T ; c0 likewise ----------------
// h0 is written PACKED (4x bf16 per u64) into the exchange buffer, slot 0.
__global__ void k_init(const float* __restrict__ sums,
                       const float* __restrict__ w1h, const float* __restrict__ w2h,
                       const float* __restrict__ w1c, const float* __restrict__ w2c,
                       u64* __restrict__ hexch, float* __restrict__ c0) {
  const int b = blockIdx.x, t = threadIdx.x;
  __shared__ float s_in[CIN], s_h[CIN], s_c[CIN];
  __shared__ __align__(8) short s_hb[HID];
  if (t < CIN) s_in[t] = sums[b * CIN + t];
  __syncthreads();
  {
    const int j = t & 127;
    const float* w = (t < CIN ? w1h : w1c) + j * CIN;
    float a = 0.f;
    #pragma unroll 8
    for (int k = 0; k < CIN; k++) a += s_in[k] * w[k];
    a = fmaxf(a, 0.f);
    if (t < CIN) s_h[j] = a; else s_c[j] = a;
  }
  __syncthreads();
  float ah = 0.f, ac = 0.f;
  const float* wh = w2h + t * CIN;
  const float* wc = w2c + t * CIN;
  #pragma unroll 8
  for (int k = 0; k < CIN; k++) { ah += s_h[k] * wh[k]; ac += s_c[k] * wc[k]; }
  s_hb[t] = f2bf(ah);
  c0[b * HID + t] = ac;
  __syncthreads();
  if (t < HID / 4)
    hexch[(size_t)b * 64 + t] = *(const u64*)&s_hb[t * 4];   // buffer 0
}

// ---------------- persistent LSTM recurrence (MFMA, atomic h-exchange) ----------------
// 64 blocks x 1024 threads = 16 groups (16 batches) x 4 members (64 hid = 256 rows).
// R10 lesson: per-step cost was the cache-maintenance protocol (threadfence = L2
// writeback, acquire = L2 invalidate, per block per step). This round exchanges h
// THROUGH THE COHERENT POINT: packed 4xbf16 u64 relaxed agent-scope atomic
// stores/loads (coherent across XCDs without fences, m20), flag barrier relaxed.
// Zero cache-maintenance ops in the steady-state loop.
__launch_bounds__(1024, 1)
__global__ void k_lstm(const float* __restrict__ x, const int* __restrict__ lens,
                       const float* __restrict__ Wih, const float* __restrict__ Whh,
                       const float* __restrict__ bih, const float* __restrict__ bhh,
                       const float* __restrict__ c0,
                       u64* __restrict__ hexch, float* __restrict__ pp,
                       int* __restrict__ ctrs) {
  const int p    = blockIdx.x;        // 0..63
  const int m    = p >> 4;            // member 0..3 (hidden slice of 64)
  const int grp  = p & 15;            // batch group 0..15
  const int bat0 = grp * BPG;
  const int hid0 = m * HPB;

  const int t   = threadIdx.x;        // 0..1023
  const int w   = t >> 6;             // wave 0..15
  const int kq  = w & 3;              // K-quarter
  const int mq  = w >> 2;             // M-quadrant (4 M-tiles each)
  const int l15 = t & 15;             // MFMA lane col
  const int hi  = (t >> 4) & 3;       // MFMA lane row-group

  const int j2 = t & 63, b2 = t >> 6;           // update role: (hid j2, batch b2) 64x16
  const int ch = t & 127, bp2 = (t >> 7) * 2;   // x staging: channel + batch-pair

  __shared__ __align__(16) short s_hxb[BPG * HXS];   // bf16 [16 b][384k+pad] = 12.5 KB
  __shared__ float s_part[4 * RPB * SPP];            // 69.6 KB K-quarter partials
  __shared__ float s_red[1024];
  __shared__ __align__(8) short s_hvalb[1024];       // raw bf16 h staging for pack
  __shared__ int   s_lens[NB];
  __shared__ int   s_off[BPG], s_len[BPG];

  if (t < NB) s_lens[t] = lens[t];
  __syncthreads();
  if (t < BPG) {
    int off = 0;
    for (int k = 0; k < bat0 + t; k++) off += s_lens[k];
    s_off[t] = off;
    s_len[t] = s_lens[bat0 + t];
  }
  __syncthreads();

  // ---- persistent W as MFMA A-fragments ----
  // local row lr = mt*16 + l15  (mt = mq*4 + i); gate = lr>>6, hidLocal = lr&63
  // k = kq*96 + kc*32 + hi*8 + e   (A and B share this k-map, so any k-permute cancels)
  #define LOADA(AV, MT, KC) do {                                                   \
    const int lr_   = (MT) * 16 + l15;                                             \
    const int grow_ = (lr_ >> 6) * HID + hid0 + (lr_ & 63);                        \
    const int k0_   = kq * 96 + (KC) * 32 + hi * 8;                                \
    const float* src_ = (k0_ < CIN) ? (Wih + (size_t)grow_ * CIN + k0_)            \
                                    : (Whh + (size_t)grow_ * HID + (k0_ - CIN));   \
    const float4 f0_ = *(const float4*)(src_);                                     \
    const float4 f1_ = *(const float4*)(src_ + 4);                                 \
    AV[0]=f2bf(f0_.x); AV[1]=f2bf(f0_.y); AV[2]=f2bf(f0_.z); AV[3]=f2bf(f0_.w);    \
    AV[4]=f2bf(f1_.x); AV[5]=f2bf(f1_.y); AV[6]=f2bf(f1_.z); AV[7]=f2bf(f1_.w);    \
  } while (0)
  bf16x8 a00, a01, a02, a10, a11, a12, a20, a21, a22, a30, a31, a32;
  LOADA(a00, mq*4+0, 0); LOADA(a01, mq*4+0, 1); LOADA(a02, mq*4+0, 2);
  LOADA(a10, mq*4+1, 0); LOADA(a11, mq*4+1, 1); LOADA(a12, mq*4+1, 2);
  LOADA(a20, mq*4+2, 0); LOADA(a21, mq*4+2, 1); LOADA(a22, mq*4+2, 2);
  LOADA(a30, mq*4+3, 0); LOADA(a31, mq*4+3, 1); LOADA(a32, mq*4+3, 2);

  // update-role biases (gate order i,f,g,o)
  const float bias0 = bih[0*HID + hid0 + j2] + bhh[0*HID + hid0 + j2];
  const float bias1 = bih[1*HID + hid0 + j2] + bhh[1*HID + hid0 + j2];
  const float bias2 = bih[2*HID + hid0 + j2] + bhh[2*HID + hid0 + j2];
  const float bias3 = bih[3*HID + hid0 + j2] + bhh[3*HID + hid0 + j2];

  float c_reg = c0[(size_t)(bat0 + b2) * HID + hid0 + j2];

  float xp0, xp1;
  #define PREFX(S) do { \
    xp0 = ((S) < s_len[bp2+0]) ? x[(size_t)(s_off[bp2+0]+(S))*CIN+ch] : 0.f; \
    xp1 = ((S) < s_len[bp2+1]) ? x[(size_t)(s_off[bp2+1]+(S))*CIN+ch] : 0.f; \
  } while (0)
  // h staging: one u64 atomic load per thread = 4 bf16 -> direct 8B LDS write
  #define STAGE(S) do { \
    s_hxb[(bp2+0)*HXS+ch] = f2bf(xp0); \
    s_hxb[(bp2+1)*HXS+ch] = f2bf(xp1); \
    const int b_ = t >> 6, q64_ = t & 63; \
    const u64 v_ = __hip_atomic_load( \
        hexch + ((size_t)((S) & 1) * NB + bat0 + b_) * 64 + q64_, \
        __ATOMIC_RELAXED, __HIP_MEMORY_SCOPE_AGENT); \
    *(u64*)&s_hxb[b_ * HXS + CIN + q64_ * 4] = v_; \
  } while (0)

  PREFX(0);
  STAGE(0);
  __syncthreads();

  for (int s = 0; s < TST; s++) {
    // ---- gate K-quarter partials via MFMA: 3 B-frags x 4 M-tiles per wave ----
    f32x4 d0 = {0.f,0.f,0.f,0.f}, d1 = {0.f,0.f,0.f,0.f};
    f32x4 d2 = {0.f,0.f,0.f,0.f}, d3 = {0.f,0.f,0.f,0.f};
    {
      const short* hxb = s_hxb + l15 * HXS + kq * 96 + hi * 8;
      bf16x8 bv;
      bv = *(const bf16x8*)(hxb + 0);
      d0 = __builtin_amdgcn_mfma_f32_16x16x32_bf16(a00, bv, d0, 0, 0, 0);
      d1 = __builtin_amdgcn_mfma_f32_16x16x32_bf16(a10, bv, d1, 0, 0, 0);
      d2 = __builtin_amdgcn_mfma_f32_16x16x32_bf16(a20, bv, d2, 0, 0, 0);
      d3 = __builtin_amdgcn_mfma_f32_16x16x32_bf16(a30, bv, d3, 0, 0, 0);
      bv = *(const bf16x8*)(hxb + 32);
      d0 = __builtin_amdgcn_mfma_f32_16x16x32_bf16(a01, bv, d0, 0, 0, 0);
      d1 = __builtin_amdgcn_mfma_f32_16x16x32_bf16(a11, bv, d1, 0, 0, 0);
      d2 = __builtin_amdgcn_mfma_f32_16x16x32_bf16(a21, bv, d2, 0, 0, 0);
      d3 = __builtin_amdgcn_mfma_f32_16x16x32_bf16(a31, bv, d3, 0, 0, 0);
      bv = *(const bf16x8*)(hxb + 64);
      d0 = __builtin_amdgcn_mfma_f32_16x16x32_bf16(a02, bv, d0, 0, 0, 0);
      d1 = __builtin_amdgcn_mfma_f32_16x16x32_bf16(a12, bv, d1, 0, 0, 0);
      d2 = __builtin_amdgcn_mfma_f32_16x16x32_bf16(a22, bv, d2, 0, 0, 0);
      d3 = __builtin_amdgcn_mfma_f32_16x16x32_bf16(a32, bv, d3, 0, 0, 0);
    }
    if (s < TST - 1) PREFX(s + 1);   // x loads drain during update/barrier

    // C layout (m89-verified): col = lane&15, local row = 16*mt + hi*4 + reg
    {
      float* spc = s_part + (size_t)(kq * RPB + mq * 64 + hi * 4) * SPP + l15;
      spc[(0*16 + 0)*SPP] = d0[0]; spc[(0*16 + 1)*SPP] = d0[1];
      spc[(0*16 + 2)*SPP] = d0[2]; spc[(0*16 + 3)*SPP] = d0[3];
      spc[(1*16 + 0)*SPP] = d1[0]; spc[(1*16 + 1)*SPP] = d1[1];
      spc[(1*16 + 2)*SPP] = d1[2]; spc[(1*16 + 3)*SPP] = d1[3];
      spc[(2*16 + 0)*SPP] = d2[0]; spc[(2*16 + 1)*SPP] = d2[1];
      spc[(2*16 + 2)*SPP] = d2[2]; spc[(2*16 + 3)*SPP] = d2[3];
      spc[(3*16 + 0)*SPP] = d3[0]; spc[(3*16 + 1)*SPP] = d3[1];
      spc[(3*16 + 2)*SPP] = d3[2]; spc[(3*16 + 3)*SPP] = d3[3];
    }
    __syncthreads();

    // ---- update: thread (j2,b2) sums 4 K-quarters for its 4 gate rows ----
    float g0 = bias0, g1 = bias1, g2 = bias2, g3 = bias3;
    #pragma unroll
    for (int q = 0; q < 4; q++) {
      const float* spq = s_part + (size_t)(q * RPB + j2) * SPP + b2;
      g0 += spq[(0 * 64) * SPP];
      g1 += spq[(1 * 64) * SPP];
      g2 += spq[(2 * 64) * SPP];
      g3 += spq[(3 * 64) * SPP];
    }
    c_reg = fmaf(sigm(g1), c_reg, sigm(g0) * tanh_(g2));
    const float h = sigm(g3) * tanh_(c_reg);

    s_hvalb[b2 * HPB + j2] = f2bf(h);
    s_red[b2 * HPB + j2]   = (bat0 + b2 < s_lens[s]) ? h : 0.f;
    __syncthreads();

    // ---- publish h (packed u64 atomic stores to the coherent point) + pp write ----
    if (t < 256) {
      const int bb = t >> 4, qq = t & 15;
      const u64 v = *(const u64*)&s_hvalb[bb * HPB + qq * 4];
      __hip_atomic_store(
          hexch + ((size_t)((s + 1) & 1) * NB + bat0 + bb) * 64 + (hid0 >> 2) + qq,
          v, __ATOMIC_RELAXED, __HIP_MEMORY_SCOPE_AGENT);
    }
    if (t >= 512 && t < 512 + HPB) {
      const int jl = t - 512;
      float ps = 0.f;
      #pragma unroll
      for (int b = 0; b < BPG; b++) ps += s_red[b * HPB + jl];
      pp[(((size_t)s * GRPS + grp) * MEMB + m) * HPB + jl] = ps;
    }

    if (s == TST - 1) break;

    __syncthreads();   // compiler emits vmcnt(0) before s_barrier -> stores are at L2/fabric

    // ---- 4-block group barrier: relaxed add + relaxed spin (no fences, no inv) ----
    if (t == 0) {
      __hip_atomic_fetch_add(ctrs + grp * 16, 1, __ATOMIC_RELAXED, __HIP_MEMORY_SCOPE_AGENT);
      const int target = MEMB * (s + 1);
      while (__hip_atomic_load(ctrs + grp * 16, __ATOMIC_RELAXED, __HIP_MEMORY_SCOPE_AGENT) < target)
        __builtin_amdgcn_s_sleep(1);
      asm volatile("" ::: "memory");
    }
    __syncthreads();
    STAGE(s + 1);
    __syncthreads();
  }
}

// ---------------- masked batch-mean + FC ----------------
__global__ void k_out(const float* __restrict__ pp, const int* __restrict__ lens,
                      const float* __restrict__ fcW, const float* __restrict__ fcb,
                      float* __restrict__ out) {
  const int i = blockIdx.x, t = threadIdx.x;
  __shared__ float s_fc[HID];
  const int cnt = min(lens[i], NB);
  const int m = t >> 6, jl = t & 63;             // hid = t
  float a = 0.f;
  const float* base = pp + ((size_t)i * GRPS * MEMB + m) * HPB + jl;
  #pragma unroll 4
  for (int g = 0; g < GRPS; g++) a += base[(size_t)g * MEMB * HPB];
  s_fc[t] = a / (float)cnt;
  __syncthreads();
  for (int n = t; n < NCLS; n += 256) {
    float acc = fcb[n];
    const float4* w4 = (const float4*)(fcW + (size_t)n * HID);
    #pragma unroll 8
    for (int k4 = 0; k4 < HID / 4; k4++) {
      const float4 wv = w4[k4];
      acc = fmaf(s_fc[4*k4+0], wv.x, acc);
      acc = fmaf(s_fc[4*k4+1], wv.y, acc);
      acc = fmaf(s_fc[4*k4+2], wv.z, acc);
      acc = fmaf(s_fc[4*k4+3], wv.w, acc);
    }
    out[(size_t)i * NCLS + n] = acc;
  }
}

extern "C" void kernel_launch(void* const* d_in, const int* in_sizes, int n_in,
                              void* d_out, int out_size, void* d_ws, size_t ws_size,
                              hipStream_t stream) {
  const float* x    = (const float*)d_in[0];
  const int*   lens = (const int*)  d_in[1];
  const float* Wih  = (const float*)d_in[2];
  const float* Whh  = (const float*)d_in[3];
  const float* bih  = (const float*)d_in[4];
  const float* bhh  = (const float*)d_in[5];
  const float* w1h  = (const float*)d_in[6];
  const float* w2h  = (const float*)d_in[7];
  const float* w1c  = (const float*)d_in[8];
  const float* w2c  = (const float*)d_in[9];
  const float* fcW  = (const float*)d_in[10];
  const float* fcb  = (const float*)d_in[11];
  float* out = (float*)d_out;

  char* ws = (char*)d_ws;
  float* sums = (float*)(ws + WS_SUMS);
  u64*   hex  = (u64*)  (ws + WS_HEX);
  float* c0   = (float*)(ws + WS_C0);
  int*   ctrs = (int*)  (ws + WS_CTRS);
  float* pp   = (float*)(ws + WS_PP);

  hipMemsetAsync(ctrs, 0, GRPS * 16 * sizeof(int), stream);  // barrier ctrs zeroed every call
  k_segsum<<<NB, 256, 0, stream>>>(x, lens, sums);
  k_init  <<<NB, 256, 0, stream>>>(sums, w1h, w2h, w1c, w2c, hex, c0);
  k_lstm  <<<GRPS * MEMB, 1024, 0, stream>>>(x, lens, Wih, Whh, bih, bhh, c0, hex, pp, ctrs);
  k_out   <<<NB, 256, 0, stream>>>(pp, lens, fcW, fcb, out);
}

// Round 12
// 853.463 us; speedup vs baseline: 57.7769x; 1.0279x over previous
//
#include <hip/hip_runtime.h>
#include <hip/hip_bf16.h>
#include <stdint.h>

#define NB    256   // batch / segments
#define CIN   128   // input channels
#define HID   256   // hidden
#define TST   256   // only first 256 timesteps matter for the output
#define NCLS  400

#define GRPS  16    // batch groups
#define MEMB  4     // blocks per group (hidden-slice members)
#define BPG   16    // batches per group
#define HPB   64    // hidden units per block
#define RPB   256   // gate rows per block (4 gates x 64 hid)
#define HXS   392   // s_hxb row stride in SHORTS (384 + 8 pad)
#define SPP   17    // s_part row stride in floats

// ---- workspace layout (bytes) ----
#define WS_SUMS   0u                       // 256*128*4   = 131072
#define WS_HEX    131072u                  // u64[2][256][64] = 262144 packed-bf16 h exchange
#define WS_C0     655360u                  // 256*256*4   = 262144
#define WS_TAGS   917504u                  // int tags[2][16][4] padded x4 = 2048
#define WS_PP     1048576u                 // 256*16*4*64*4 = 4194304 masked partials

typedef __attribute__((ext_vector_type(8))) short bf16x8;  // 8 bf16 = one MFMA A/B frag
typedef __attribute__((ext_vector_type(4))) float f32x4;   // MFMA accumulator
typedef unsigned long long u64;

__device__ __forceinline__ short f2bf(float f) {
  __hip_bfloat16 h = __float2bfloat16(f);
  return *reinterpret_cast<short*>(&h);
}
__device__ __forceinline__ float sigm(float v) { return 1.0f / (1.0f + __expf(-v)); }
__device__ __forceinline__ float tanh_(float v) {
  v = fminf(fmaxf(v, -15.0f), 15.0f);
  const float e = __expf(2.0f * v);
  return (e - 1.0f) / (e + 1.0f);
}

// ---------------- segment sums (the "input_means" that are really sums) ----------------
__global__ void k_segsum(const float* __restrict__ x, const int* __restrict__ lens,
                         float* __restrict__ sums) {
  const int b = blockIdx.x, t = threadIdx.x;
  __shared__ int   s_l[NB];
  __shared__ int   s_red[256];
  __shared__ float s_f[CIN];
  s_l[t] = lens[t];
  __syncthreads();
  int part = 0;
  for (int i = t; i < b; i += 256) part += s_l[i];
  s_red[t] = part; __syncthreads();
  for (int k = 128; k > 0; k >>= 1) { if (t < k) s_red[t] += s_red[t + k]; __syncthreads(); }
  const int off = s_red[0];
  const int len = s_l[b];
  const int c = t & 127, half = t >> 7;
  float a = 0.f;
  for (int r = half; r < len; r += 2) a += x[(size_t)(off + r) * CIN + c];
  if (half) s_f[c] = a;
  __syncthreads();
  if (!half) sums[b * CIN + c] = a + s_f[c];
}

// ---------------- h0 = relu(sums@W1h^T)@W2h^T ; c0 likewise ----------------
// h0 is written PACKED (4x bf16 per u64) into the exchange buffer, slot 0.
__global__ void k_init(const float* __restrict__ sums,
                       const float* __restrict__ w1h, const float* __restrict__ w2h,
                       const float* __restrict__ w1c, const float* __restrict__ w2c,
                       u64* __restrict__ hexch, float* __restrict__ c0) {
  const int b = blockIdx.x, t = threadIdx.x;
  __shared__ float s_in[CIN], s_h[CIN], s_c[CIN];
  __shared__ __align__(8) short s_hb[HID];
  if (t < CIN) s_in[t] = sums[b * CIN + t];
  __syncthreads();
  {
    const int j = t & 127;
    const float* w = (t < CIN ? w1h : w1c) + j * CIN;
    float a = 0.f;
    #pragma unroll 8
    for (int k = 0; k < CIN; k++) a += s_in[k] * w[k];
    a = fmaxf(a, 0.f);
    if (t < CIN) s_h[j] = a; else s_c[j] = a;
  }
  __syncthreads();
  float ah = 0.f, ac = 0.f;
  const float* wh = w2h + t * CIN;
  const float* wc = w2c + t * CIN;
  #pragma unroll 8
  for (int k = 0; k < CIN; k++) { ah += s_h[k] * wh[k]; ac += s_c[k] * wc[k]; }
  s_hb[t] = f2bf(ah);
  c0[b * HID + t] = ac;
  __syncthreads();
  if (t < HID / 4)
    hexch[(size_t)b * 64 + t] = *(const u64*)&s_hb[t * 4];   // buffer 0
}

// ---------------- persistent LSTM recurrence (MFMA, tag-gated dataflow) ----------------
// 64 blocks x 1024 threads = 16 groups (16 batches) x 4 members (64 hid = 256 rows).
// R11 lesson: counter-barrier serializes max-of-4 producers through one spinning
// thread + extra barrier broadcast. This round: DATAFLOW. Producer publishes its h
// slice, drains (syncthreads -> vmcnt(0) = stores acked at coherence point), then
// t0 stores tags[slot][grp][m] = s+1 (relaxed). Consumers poll only their
// producer's tag, per-lane, then load payload -- members unblock independently.
// Own slice short-circuits through LDS. Depth-2 ring safe: entering step s
// requires all tags >= s which implies all members finished STAGE(s-1).
__launch_bounds__(1024, 1)
__global__ void k_lstm(const float* __restrict__ x, const int* __restrict__ lens,
                       const float* __restrict__ Wih, const float* __restrict__ Whh,
                       const float* __restrict__ bih, const float* __restrict__ bhh,
                       const float* __restrict__ c0,
                       u64* __restrict__ hexch, float* __restrict__ pp,
                       int* __restrict__ tags) {
  const int p    = blockIdx.x;        // 0..63
  const int m    = p >> 4;            // member 0..3 (hidden slice of 64)
  const int grp  = p & 15;            // batch group 0..15 (members stride 16 -> same XCD)
  const int bat0 = grp * BPG;
  const int hid0 = m * HPB;

  const int t   = threadIdx.x;        // 0..1023
  const int w   = t >> 6;             // wave 0..15
  const int kq  = w & 3;              // K-quarter
  const int mq  = w >> 2;             // M-quadrant (4 M-tiles each)
  const int l15 = t & 15;             // MFMA lane col
  const int hi  = (t >> 4) & 3;       // MFMA lane row-group

  const int j2 = t & 63, b2 = t >> 6;           // update role: (hid j2, batch b2) 64x16
  const int ch = t & 127, bp2 = (t >> 7) * 2;   // x staging: channel + batch-pair

  __shared__ __align__(16) short s_hxb[BPG * HXS];   // bf16 [16 b][384k+pad] = 12.5 KB
  __shared__ float s_part[4 * RPB * SPP];            // 69.6 KB K-quarter partials
  __shared__ float s_red[1024];
  __shared__ __align__(8) short s_hvalb[1024];       // raw bf16 h staging for pack
  __shared__ int   s_lens[NB];
  __shared__ int   s_off[BPG], s_len[BPG];

  if (t < NB) s_lens[t] = lens[t];
  __syncthreads();
  if (t < BPG) {
    int off = 0;
    for (int k = 0; k < bat0 + t; k++) off += s_lens[k];
    s_off[t] = off;
    s_len[t] = s_lens[bat0 + t];
  }
  __syncthreads();

  // ---- persistent W as MFMA A-fragments ----
  // local row lr = mt*16 + l15  (mt = mq*4 + i); gate = lr>>6, hidLocal = lr&63
  // k = kq*96 + kc*32 + hi*8 + e   (A and B share this k-map, so any k-permute cancels)
  #define LOADA(AV, MT, KC) do {                                                   \
    const int lr_   = (MT) * 16 + l15;                                             \
    const int grow_ = (lr_ >> 6) * HID + hid0 + (lr_ & 63);                        \
    const int k0_   = kq * 96 + (KC) * 32 + hi * 8;                                \
    const float* src_ = (k0_ < CIN) ? (Wih + (size_t)grow_ * CIN + k0_)            \
                                    : (Whh + (size_t)grow_ * HID + (k0_ - CIN));   \
    const float4 f0_ = *(const float4*)(src_);                                     \
    const float4 f1_ = *(const float4*)(src_ + 4);                                 \
    AV[0]=f2bf(f0_.x); AV[1]=f2bf(f0_.y); AV[2]=f2bf(f0_.z); AV[3]=f2bf(f0_.w);    \
    AV[4]=f2bf(f1_.x); AV[5]=f2bf(f1_.y); AV[6]=f2bf(f1_.z); AV[7]=f2bf(f1_.w);    \
  } while (0)
  bf16x8 a00, a01, a02, a10, a11, a12, a20, a21, a22, a30, a31, a32;
  LOADA(a00, mq*4+0, 0); LOADA(a01, mq*4+0, 1); LOADA(a02, mq*4+0, 2);
  LOADA(a10, mq*4+1, 0); LOADA(a11, mq*4+1, 1); LOADA(a12, mq*4+1, 2);
  LOADA(a20, mq*4+2, 0); LOADA(a21, mq*4+2, 1); LOADA(a22, mq*4+2, 2);
  LOADA(a30, mq*4+3, 0); LOADA(a31, mq*4+3, 1); LOADA(a32, mq*4+3, 2);

  // update-role biases (gate order i,f,g,o)
  const float bias0 = bih[0*HID + hid0 + j2] + bhh[0*HID + hid0 + j2];
  const float bias1 = bih[1*HID + hid0 + j2] + bhh[1*HID + hid0 + j2];
  const float bias2 = bih[2*HID + hid0 + j2] + bhh[2*HID + hid0 + j2];
  const float bias3 = bih[3*HID + hid0 + j2] + bhh[3*HID + hid0 + j2];

  float c_reg = c0[(size_t)(bat0 + b2) * HID + hid0 + j2];

  float xp0, xp1;
  #define PREFX(S) do { \
    xp0 = ((S) < s_len[bp2+0]) ? x[(size_t)(s_off[bp2+0]+(S))*CIN+ch] : 0.f; \
    xp1 = ((S) < s_len[bp2+1]) ? x[(size_t)(s_off[bp2+1]+(S))*CIN+ch] : 0.f; \
  } while (0)
  // h staging: own slice from LDS; partner slices tag-gated then one u64 load
  #define STAGE(S) do { \
    s_hxb[(bp2+0)*HXS+ch] = f2bf(xp0); \
    s_hxb[(bp2+1)*HXS+ch] = f2bf(xp1); \
    const int b_ = t >> 6, q64_ = t & 63; \
    const int mem_ = q64_ >> 4; \
    if (mem_ == m && (S) > 0) { \
      *(u64*)&s_hxb[b_ * HXS + CIN + q64_ * 4] = \
          *(const u64*)&s_hvalb[b_ * HPB + (q64_ & 15) * 4]; \
    } else { \
      int* tg_ = tags + (((S) & 1) * GRPS + grp) * 16 + mem_ * 4; \
      if (__hip_atomic_load(tg_, __ATOMIC_RELAXED, __HIP_MEMORY_SCOPE_AGENT) < (S)) { \
        while (__hip_atomic_load(tg_, __ATOMIC_RELAXED, __HIP_MEMORY_SCOPE_AGENT) < (S)) \
          __builtin_amdgcn_s_sleep(1); \
      } \
      const u64 v_ = __hip_atomic_load( \
          hexch + ((size_t)((S) & 1) * NB + bat0 + b_) * 64 + q64_, \
          __ATOMIC_RELAXED, __HIP_MEMORY_SCOPE_AGENT); \
      *(u64*)&s_hxb[b_ * HXS + CIN + q64_ * 4] = v_; \
    } \
  } while (0)

  PREFX(0);
  STAGE(0);
  __syncthreads();

  for (int s = 0; s < TST; s++) {
    // ---- gate K-quarter partials via MFMA: 3 B-frags x 4 M-tiles per wave ----
    f32x4 d0 = {0.f,0.f,0.f,0.f}, d1 = {0.f,0.f,0.f,0.f};
    f32x4 d2 = {0.f,0.f,0.f,0.f}, d3 = {0.f,0.f,0.f,0.f};
    {
      const short* hxb = s_hxb + l15 * HXS + kq * 96 + hi * 8;
      bf16x8 bv;
      bv = *(const bf16x8*)(hxb + 0);
      d0 = __builtin_amdgcn_mfma_f32_16x16x32_bf16(a00, bv, d0, 0, 0, 0);
      d1 = __builtin_amdgcn_mfma_f32_16x16x32_bf16(a10, bv, d1, 0, 0, 0);
      d2 = __builtin_amdgcn_mfma_f32_16x16x32_bf16(a20, bv, d2, 0, 0, 0);
      d3 = __builtin_amdgcn_mfma_f32_16x16x32_bf16(a30, bv, d3, 0, 0, 0);
      bv = *(const bf16x8*)(hxb + 32);
      d0 = __builtin_amdgcn_mfma_f32_16x16x32_bf16(a01, bv, d0, 0, 0, 0);
      d1 = __builtin_amdgcn_mfma_f32_16x16x32_bf16(a11, bv, d1, 0, 0, 0);
      d2 = __builtin_amdgcn_mfma_f32_16x16x32_bf16(a21, bv, d2, 0, 0, 0);
      d3 = __builtin_amdgcn_mfma_f32_16x16x32_bf16(a31, bv, d3, 0, 0, 0);
      bv = *(const bf16x8*)(hxb + 64);
      d0 = __builtin_amdgcn_mfma_f32_16x16x32_bf16(a02, bv, d0, 0, 0, 0);
      d1 = __builtin_amdgcn_mfma_f32_16x16x32_bf16(a12, bv, d1, 0, 0, 0);
      d2 = __builtin_amdgcn_mfma_f32_16x16x32_bf16(a22, bv, d2, 0, 0, 0);
      d3 = __builtin_amdgcn_mfma_f32_16x16x32_bf16(a32, bv, d3, 0, 0, 0);
    }
    if (s < TST - 1) PREFX(s + 1);   // x loads drain during update phase

    // C layout (m89-verified): col = lane&15, local row = 16*mt + hi*4 + reg
    {
      float* spc = s_part + (size_t)(kq * RPB + mq * 64 + hi * 4) * SPP + l15;
      spc[(0*16 + 0)*SPP] = d0[0]; spc[(0*16 + 1)*SPP] = d0[1];
      spc[(0*16 + 2)*SPP] = d0[2]; spc[(0*16 + 3)*SPP] = d0[3];
      spc[(1*16 + 0)*SPP] = d1[0]; spc[(1*16 + 1)*SPP] = d1[1];
      spc[(1*16 + 2)*SPP] = d1[2]; spc[(1*16 + 3)*SPP] = d1[3];
      spc[(2*16 + 0)*SPP] = d2[0]; spc[(2*16 + 1)*SPP] = d2[1];
      spc[(2*16 + 2)*SPP] = d2[2]; spc[(2*16 + 3)*SPP] = d2[3];
      spc[(3*16 + 0)*SPP] = d3[0]; spc[(3*16 + 1)*SPP] = d3[1];
      spc[(3*16 + 2)*SPP] = d3[2]; spc[(3*16 + 3)*SPP] = d3[3];
    }
    __syncthreads();

    // ---- update: thread (j2,b2) sums 4 K-quarters for its 4 gate rows ----
    float g0 = bias0, g1 = bias1, g2 = bias2, g3 = bias3;
    #pragma unroll
    for (int q = 0; q < 4; q++) {
      const float* spq = s_part + (size_t)(q * RPB + j2) * SPP + b2;
      g0 += spq[(0 * 64) * SPP];
      g1 += spq[(1 * 64) * SPP];
      g2 += spq[(2 * 64) * SPP];
      g3 += spq[(3 * 64) * SPP];
    }
    c_reg = fmaf(sigm(g1), c_reg, sigm(g0) * tanh_(g2));
    const float h = sigm(g3) * tanh_(c_reg);

    s_hvalb[b2 * HPB + j2] = f2bf(h);
    s_red[b2 * HPB + j2]   = (bat0 + b2 < s_lens[s]) ? h : 0.f;
    __syncthreads();

    // ---- publish h_{s+1} (packed u64 stores to the coherent point) + pp write ----
    if (t < 256) {
      const int bb = t >> 4, qq = t & 15;
      const u64 v = *(const u64*)&s_hvalb[bb * HPB + qq * 4];
      __hip_atomic_store(
          hexch + ((size_t)((s + 1) & 1) * NB + bat0 + bb) * 64 + (hid0 >> 2) + qq,
          v, __ATOMIC_RELAXED, __HIP_MEMORY_SCOPE_AGENT);
    }
    if (t >= 512 && t < 512 + HPB) {
      const int jl = t - 512;
      float ps = 0.f;
      #pragma unroll
      for (int b = 0; b < BPG; b++) ps += s_red[b * HPB + jl];
      pp[(((size_t)s * GRPS + grp) * MEMB + m) * HPB + jl] = ps;
    }

    if (s == TST - 1) break;

    __syncthreads();   // vmcnt(0) drain: publish stores are at the coherence point

    // ---- announce readiness; consumers poll per-member (no barrier) ----
    if (t == 0)
      __hip_atomic_store(tags + (((s + 1) & 1) * GRPS + grp) * 16 + m * 4,
                         s + 1, __ATOMIC_RELAXED, __HIP_MEMORY_SCOPE_AGENT);
    STAGE(s + 1);
    __syncthreads();
  }
}

// ---------------- masked batch-mean + FC ----------------
__global__ void k_out(const float* __restrict__ pp, const int* __restrict__ lens,
                      const float* __restrict__ fcW, const float* __restrict__ fcb,
                      float* __restrict__ out) {
  const int i = blockIdx.x, t = threadIdx.x;
  __shared__ float s_fc[HID];
  const int cnt = min(lens[i], NB);
  const int m = t >> 6, jl = t & 63;             // hid = t
  float a = 0.f;
  const float* base = pp + ((size_t)i * GRPS * MEMB + m) * HPB + jl;
  #pragma unroll 4
  for (int g = 0; g < GRPS; g++) a += base[(size_t)g * MEMB * HPB];
  s_fc[t] = a / (float)cnt;
  __syncthreads();
  for (int n = t; n < NCLS; n += 256) {
    float acc = fcb[n];
    const float4* w4 = (const float4*)(fcW + (size_t)n * HID);
    #pragma unroll 8
    for (int k4 = 0; k4 < HID / 4; k4++) {
      const float4 wv = w4[k4];
      acc = fmaf(s_fc[4*k4+0], wv.x, acc);
      acc = fmaf(s_fc[4*k4+1], wv.y, acc);
      acc = fmaf(s_fc[4*k4+2], wv.z, acc);
      acc = fmaf(s_fc[4*k4+3], wv.w, acc);
    }
    out[(size_t)i * NCLS + n] = acc;
  }
}

extern "C" void kernel_launch(void* const* d_in, const int* in_sizes, int n_in,
                              void* d_out, int out_size, void* d_ws, size_t ws_size,
                              hipStream_t stream) {
  const float* x    = (const float*)d_in[0];
  const int*   lens = (const int*)  d_in[1];
  const float* Wih  = (const float*)d_in[2];
  const float* Whh  = (const float*)d_in[3];
  const float* bih  = (const float*)d_in[4];
  const float* bhh  = (const float*)d_in[5];
  const float* w1h  = (const float*)d_in[6];
  const float* w2h  = (const float*)d_in[7];
  const float* w1c  = (const float*)d_in[8];
  const float* w2c  = (const float*)d_in[9];
  const float* fcW  = (const float*)d_in[10];
  const float* fcb  = (const float*)d_in[11];
  float* out = (float*)d_out;

  char* ws = (char*)d_ws;
  float* sums = (float*)(ws + WS_SUMS);
  u64*   hex  = (u64*)  (ws + WS_HEX);
  float* c0   = (float*)(ws + WS_C0);
  int*   tags = (int*)  (ws + WS_TAGS);
  float* pp   = (float*)(ws + WS_PP);

  hipMemsetAsync(tags, 0, 2 * GRPS * 16 * sizeof(int), stream);  // tags zeroed every call
  k_segsum<<<NB, 256, 0, stream>>>(x, lens, sums);
  k_init  <<<NB, 256, 0, stream>>>(sums, w1h, w2h, w1c, w2c, hex, c0);
  k_lstm  <<<GRPS * MEMB, 1024, 0, stream>>>(x, lens, Wih, Whh, bih, bhh, c0, hex, pp, tags);
  k_out   <<<NB, 256, 0, stream>>>(pp, lens, fcW, fcb, out);
}

// Round 13
// 836.198 us; speedup vs baseline: 58.9698x; 1.0206x over previous
//
#include <hip/hip_runtime.h>
#include <hip/hip_bf16.h>
#include <stdint.h>

#define NB    256   // batch / segments
#define CIN   128   // input channels
#define HID   256   // hidden
#define TST   256   // only first 256 timesteps matter for the output
#define NCLS  400

#define GRPS  16    // batch groups
#define MEMB  4     // blocks per group (hidden-slice members)
#define BPG   16    // batches per group
#define HPB   64    // hidden units per block
#define RPB   256   // gate rows per block (4 gates x 64 hid)
#define HXS   392   // s_hxb row stride in SHORTS (384 + 8 pad)
#define SPP   17    // s_part row stride in floats

// ---- workspace layout (bytes) ----
#define WS_SUMS   0u                       // 256*128*4 = 131072
#define WS_HEX0   131072u                  // u64[256][64] bf16-packed h0 = 131072
#define WS_HEX    262144u                  // u64[2][256][64] tagged ring = 262144
#define WS_C0     524288u                  // 256*256*4 = 262144
#define WS_PP     786432u                  // 256*16*4*64*4 = 4194304 masked partials

typedef __attribute__((ext_vector_type(8))) short bf16x8;  // 8 bf16 = one MFMA A/B frag
typedef __attribute__((ext_vector_type(4))) float f32x4;   // MFMA accumulator
typedef unsigned long long u64;

__device__ __forceinline__ short f2bf(float f) {
  __hip_bfloat16 h = __float2bfloat16(f);
  return *reinterpret_cast<short*>(&h);
}
__device__ __forceinline__ float sigm(float v) { return 1.0f / (1.0f + __expf(-v)); }
__device__ __forceinline__ float tanh_(float v) {
  v = fminf(fmaxf(v, -15.0f), 15.0f);
  const float e = __expf(2.0f * v);
  return (e - 1.0f) / (e + 1.0f);
}
// 12-bit signed fixed-point in (-1,1): abs err <= 2.44e-4 (< bf16 ulp near 1)
__device__ __forceinline__ int q12(float h) {
  int q = (int)rintf(h * 2048.f);
  q = max(-2048, min(2047, q));
  return q & 0xFFF;
}
__device__ __forceinline__ short dq12(int bits) {
  int q = (bits ^ 0x800) - 0x800;           // sign-extend 12-bit
  return f2bf((float)q * (1.0f / 2048.f));
}

// ---------------- segment sums (the "input_means" that are really sums) ----------------
__global__ void k_segsum(const float* __restrict__ x, const int* __restrict__ lens,
                         float* __restrict__ sums) {
  const int b = blockIdx.x, t = threadIdx.x;
  __shared__ int   s_l[NB];
  __shared__ int   s_red[256];
  __shared__ float s_f[CIN];
  s_l[t] = lens[t];
  __syncthreads();
  int part = 0;
  for (int i = t; i < b; i += 256) part += s_l[i];
  s_red[t] = part; __syncthreads();
  for (int k = 128; k > 0; k >>= 1) { if (t < k) s_red[t] += s_red[t + k]; __syncthreads(); }
  const int off = s_red[0];
  const int len = s_l[b];
  const int c = t & 127, half = t >> 7;
  float a = 0.f;
  for (int r = half; r < len; r += 2) a += x[(size_t)(off + r) * CIN + c];
  if (half) s_f[c] = a;
  __syncthreads();
  if (!half) sums[b * CIN + c] = a + s_f[c];
}

// ---------------- h0 = relu(sums@W1h^T)@W2h^T ; c0 likewise ----------------
// h0 written bf16-packed (4 per u64), UNTAGGED (h0 is unbounded; step-0 staging
// needs no poll -- stream order guarantees k_init completed).
__global__ void k_init(const float* __restrict__ sums,
                       const float* __restrict__ w1h, const float* __restrict__ w2h,
                       const float* __restrict__ w1c, const float* __restrict__ w2c,
                       u64* __restrict__ hex0, float* __restrict__ c0) {
  const int b = blockIdx.x, t = threadIdx.x;
  __shared__ float s_in[CIN], s_h[CIN], s_c[CIN];
  __shared__ __align__(8) short s_hb[HID];
  if (t < CIN) s_in[t] = sums[b * CIN + t];
  __syncthreads();
  {
    const int j = t & 127;
    const float* w = (t < CIN ? w1h : w1c) + j * CIN;
    float a = 0.f;
    #pragma unroll 8
    for (int k = 0; k < CIN; k++) a += s_in[k] * w[k];
    a = fmaxf(a, 0.f);
    if (t < CIN) s_h[j] = a; else s_c[j] = a;
  }
  __syncthreads();
  float ah = 0.f, ac = 0.f;
  const float* wh = w2h + t * CIN;
  const float* wc = w2c + t * CIN;
  #pragma unroll 8
  for (int k = 0; k < CIN; k++) { ah += s_h[k] * wh[k]; ac += s_c[k] * wc[k]; }
  s_hb[t] = f2bf(ah);
  c0[b * HID + t] = ac;
  __syncthreads();
  if (t < HID / 4)
    hex0[(size_t)b * 64 + t] = *(const u64*)&s_hb[t * 4];
}

// ---------------- persistent LSTM recurrence (MFMA, tagged-payload exchange) ----------------
// 64 blocks x 1024 threads = 16 groups (16 batches) x 4 members (64 hid = 256 rows).
// R11/R12 lesson: the cost is the SERIAL VISIBILITY CHAIN (drain stores -> publish
// tag -> poll tag -> load payload = 3-4 coherence-point RTTs/step). This round:
// ONE flight. u64 = {tag:16 | 4x h quantized to 12-bit fixed}. Producer lanes
// assemble via shfl_xor and fire the atomic store immediately (no drain, no tag
// op). Consumers poll their own u64 until embedded tag == step -- self-validated.
// Stale-tag cross-call hazard: ring memset to 0 each launch.
__launch_bounds__(1024, 1)
__global__ void k_lstm(const float* __restrict__ x, const int* __restrict__ lens,
                       const float* __restrict__ Wih, const float* __restrict__ Whh,
                       const float* __restrict__ bih, const float* __restrict__ bhh,
                       const float* __restrict__ c0,
                       const u64* __restrict__ hex0, u64* __restrict__ hexch,
                       float* __restrict__ pp) {
  const int p    = blockIdx.x;        // 0..63
  const int m    = p >> 4;            // member 0..3 (hidden slice of 64)
  const int grp  = p & 15;            // batch group 0..15 (members stride 16 -> same XCD)
  const int bat0 = grp * BPG;
  const int hid0 = m * HPB;

  const int t   = threadIdx.x;        // 0..1023
  const int w   = t >> 6;             // wave 0..15
  const int kq  = w & 3;              // K-quarter
  const int mq  = w >> 2;             // M-quadrant (4 M-tiles each)
  const int l15 = t & 15;             // MFMA lane col
  const int hi  = (t >> 4) & 3;       // MFMA lane row-group

  const int j2 = t & 63, b2 = t >> 6;           // update role: (hid j2, batch b2) 64x16
  const int ch = t & 127, bp2 = (t >> 7) * 2;   // x staging: channel + batch-pair

  __shared__ __align__(16) short s_hxb[BPG * HXS];   // bf16 [16 b][384k+pad] = 12.5 KB
  __shared__ float s_part[4 * RPB * SPP];            // 69.6 KB K-quarter partials
  __shared__ float s_red[1024];
  __shared__ __align__(8) short s_hvalb[1024];       // bf16 h staging (own-slice path)
  __shared__ int   s_lens[NB];
  __shared__ int   s_off[BPG], s_len[BPG];

  if (t < NB) s_lens[t] = lens[t];
  __syncthreads();
  if (t < BPG) {
    int off = 0;
    for (int k = 0; k < bat0 + t; k++) off += s_lens[k];
    s_off[t] = off;
    s_len[t] = s_lens[bat0 + t];
  }
  __syncthreads();

  // ---- persistent W as MFMA A-fragments ----
  // local row lr = mt*16 + l15  (mt = mq*4 + i); gate = lr>>6, hidLocal = lr&63
  // k = kq*96 + kc*32 + hi*8 + e   (A and B share this k-map, so any k-permute cancels)
  #define LOADA(AV, MT, KC) do {                                                   \
    const int lr_   = (MT) * 16 + l15;                                             \
    const int grow_ = (lr_ >> 6) * HID + hid0 + (lr_ & 63);                        \
    const int k0_   = kq * 96 + (KC) * 32 + hi * 8;                                \
    const float* src_ = (k0_ < CIN) ? (Wih + (size_t)grow_ * CIN + k0_)            \
                                    : (Whh + (size_t)grow_ * HID + (k0_ - CIN));   \
    const float4 f0_ = *(const float4*)(src_);                                     \
    const float4 f1_ = *(const float4*)(src_ + 4);                                 \
    AV[0]=f2bf(f0_.x); AV[1]=f2bf(f0_.y); AV[2]=f2bf(f0_.z); AV[3]=f2bf(f0_.w);    \
    AV[4]=f2bf(f1_.x); AV[5]=f2bf(f1_.y); AV[6]=f2bf(f1_.z); AV[7]=f2bf(f1_.w);    \
  } while (0)
  bf16x8 a00, a01, a02, a10, a11, a12, a20, a21, a22, a30, a31, a32;
  LOADA(a00, mq*4+0, 0); LOADA(a01, mq*4+0, 1); LOADA(a02, mq*4+0, 2);
  LOADA(a10, mq*4+1, 0); LOADA(a11, mq*4+1, 1); LOADA(a12, mq*4+1, 2);
  LOADA(a20, mq*4+2, 0); LOADA(a21, mq*4+2, 1); LOADA(a22, mq*4+2, 2);
  LOADA(a30, mq*4+3, 0); LOADA(a31, mq*4+3, 1); LOADA(a32, mq*4+3, 2);

  // update-role biases (gate order i,f,g,o)
  const float bias0 = bih[0*HID + hid0 + j2] + bhh[0*HID + hid0 + j2];
  const float bias1 = bih[1*HID + hid0 + j2] + bhh[1*HID + hid0 + j2];
  const float bias2 = bih[2*HID + hid0 + j2] + bhh[2*HID + hid0 + j2];
  const float bias3 = bih[3*HID + hid0 + j2] + bhh[3*HID + hid0 + j2];

  float c_reg = c0[(size_t)(bat0 + b2) * HID + hid0 + j2];

  float xp0, xp1;
  #define PREFX(S) do { \
    xp0 = ((S) < s_len[bp2+0]) ? x[(size_t)(s_off[bp2+0]+(S))*CIN+ch] : 0.f; \
    xp1 = ((S) < s_len[bp2+1]) ? x[(size_t)(s_off[bp2+1]+(S))*CIN+ch] : 0.f; \
  } while (0)

  // step-0 staging: plain untagged bf16 u64 from hex0 (k_init stream-ordered)
  #define STAGE0() do { \
    s_hxb[(bp2+0)*HXS+ch] = f2bf(xp0); \
    s_hxb[(bp2+1)*HXS+ch] = f2bf(xp1); \
    const int b_ = t >> 6, q64_ = t & 63; \
    const u64 v_ = hex0[(size_t)(bat0 + b_) * 64 + q64_]; \
    *(u64*)&s_hxb[b_ * HXS + CIN + q64_ * 4] = v_; \
  } while (0)

  // steady-state staging: own slice via LDS; remote = poll tagged u64, unpack
  #define STAGE(S) do { \
    s_hxb[(bp2+0)*HXS+ch] = f2bf(xp0); \
    s_hxb[(bp2+1)*HXS+ch] = f2bf(xp1); \
    const int b_ = t >> 6, q64_ = t & 63; \
    const int mem_ = q64_ >> 4; \
    if (mem_ == m) { \
      *(u64*)&s_hxb[b_ * HXS + CIN + q64_ * 4] = \
          *(const u64*)&s_hvalb[b_ * HPB + (q64_ & 15) * 4]; \
    } else { \
      const u64* src_ = hexch + ((size_t)((S) & 1) * NB + bat0 + b_) * 64 + q64_; \
      u64 v_ = __hip_atomic_load(src_, __ATOMIC_RELAXED, __HIP_MEMORY_SCOPE_AGENT); \
      while ((v_ >> 48) != (u64)(S)) { \
        __builtin_amdgcn_s_sleep(1); \
        v_ = __hip_atomic_load(src_, __ATOMIC_RELAXED, __HIP_MEMORY_SCOPE_AGENT); \
      } \
      short* dst_ = &s_hxb[b_ * HXS + CIN + q64_ * 4]; \
      dst_[0] = dq12((int)(v_        & 0xFFF)); \
      dst_[1] = dq12((int)((v_ >> 12) & 0xFFF)); \
      dst_[2] = dq12((int)((v_ >> 24) & 0xFFF)); \
      dst_[3] = dq12((int)((v_ >> 36) & 0xFFF)); \
    } \
  } while (0)

  PREFX(0);
  STAGE0();
  __syncthreads();

  for (int s = 0; s < TST; s++) {
    // ---- gate K-quarter partials via MFMA: 3 B-frags x 4 M-tiles per wave ----
    f32x4 d0 = {0.f,0.f,0.f,0.f}, d1 = {0.f,0.f,0.f,0.f};
    f32x4 d2 = {0.f,0.f,0.f,0.f}, d3 = {0.f,0.f,0.f,0.f};
    {
      const short* hxb = s_hxb + l15 * HXS + kq * 96 + hi * 8;
      bf16x8 bv;
      bv = *(const bf16x8*)(hxb + 0);
      d0 = __builtin_amdgcn_mfma_f32_16x16x32_bf16(a00, bv, d0, 0, 0, 0);
      d1 = __builtin_amdgcn_mfma_f32_16x16x32_bf16(a10, bv, d1, 0, 0, 0);
      d2 = __builtin_amdgcn_mfma_f32_16x16x32_bf16(a20, bv, d2, 0, 0, 0);
      d3 = __builtin_amdgcn_mfma_f32_16x16x32_bf16(a30, bv, d3, 0, 0, 0);
      bv = *(const bf16x8*)(hxb + 32);
      d0 = __builtin_amdgcn_mfma_f32_16x16x32_bf16(a01, bv, d0, 0, 0, 0);
      d1 = __builtin_amdgcn_mfma_f32_16x16x32_bf16(a11, bv, d1, 0, 0, 0);
      d2 = __builtin_amdgcn_mfma_f32_16x16x32_bf16(a21, bv, d2, 0, 0, 0);
      d3 = __builtin_amdgcn_mfma_f32_16x16x32_bf16(a31, bv, d3, 0, 0, 0);
      bv = *(const bf16x8*)(hxb + 64);
      d0 = __builtin_amdgcn_mfma_f32_16x16x32_bf16(a02, bv, d0, 0, 0, 0);
      d1 = __builtin_amdgcn_mfma_f32_16x16x32_bf16(a12, bv, d1, 0, 0, 0);
      d2 = __builtin_amdgcn_mfma_f32_16x16x32_bf16(a22, bv, d2, 0, 0, 0);
      d3 = __builtin_amdgcn_mfma_f32_16x16x32_bf16(a32, bv, d3, 0, 0, 0);
    }
    if (s < TST - 1) PREFX(s + 1);

    // C layout (m89-verified): col = lane&15, local row = 16*mt + hi*4 + reg
    {
      float* spc = s_part + (size_t)(kq * RPB + mq * 64 + hi * 4) * SPP + l15;
      spc[(0*16 + 0)*SPP] = d0[0]; spc[(0*16 + 1)*SPP] = d0[1];
      spc[(0*16 + 2)*SPP] = d0[2]; spc[(0*16 + 3)*SPP] = d0[3];
      spc[(1*16 + 0)*SPP] = d1[0]; spc[(1*16 + 1)*SPP] = d1[1];
      spc[(1*16 + 2)*SPP] = d1[2]; spc[(1*16 + 3)*SPP] = d1[3];
      spc[(2*16 + 0)*SPP] = d2[0]; spc[(2*16 + 1)*SPP] = d2[1];
      spc[(2*16 + 2)*SPP] = d2[2]; spc[(2*16 + 3)*SPP] = d2[3];
      spc[(3*16 + 0)*SPP] = d3[0]; spc[(3*16 + 1)*SPP] = d3[1];
      spc[(3*16 + 2)*SPP] = d3[2]; spc[(3*16 + 3)*SPP] = d3[3];
    }
    __syncthreads();

    // ---- update: thread (j2,b2) sums 4 K-quarters for its 4 gate rows ----
    float g0 = bias0, g1 = bias1, g2 = bias2, g3 = bias3;
    #pragma unroll
    for (int q = 0; q < 4; q++) {
      const float* spq = s_part + (size_t)(q * RPB + j2) * SPP + b2;
      g0 += spq[(0 * 64) * SPP];
      g1 += spq[(1 * 64) * SPP];
      g2 += spq[(2 * 64) * SPP];
      g3 += spq[(3 * 64) * SPP];
    }
    c_reg = fmaf(sigm(g1), c_reg, sigm(g0) * tanh_(g2));
    const float h = sigm(g3) * tanh_(c_reg);

    // ---- IMMEDIATE tagged publish: quantize, wave-pack via shfl, lane%4 fires ----
    {
      const int q  = q12(h);                           // lane j2 (contiguous in wave)
      const int qp = q | (__shfl_xor(q, 1) << 12);     // even lanes: q[L]|q[L+1]<<12
      const int qo = __shfl_xor(qp, 2);                // L%4==0: q[L+2]|q[L+3]<<12
      if ((t & 3) == 0) {
        const u64 v = ((u64)(s + 1) << 48) |
                      ((u64)(unsigned)(qo & 0xFFFFFF) << 24) |
                      (u64)(unsigned)(qp & 0xFFFFFF);
        __hip_atomic_store(
            hexch + ((size_t)((s + 1) & 1) * NB + bat0 + b2) * 64 + (hid0 >> 2) + (j2 >> 2),
            v, __ATOMIC_RELAXED, __HIP_MEMORY_SCOPE_AGENT);
      }
    }
    s_hvalb[b2 * HPB + j2] = f2bf(h);
    s_red[b2 * HPB + j2]   = (bat0 + b2 < s_lens[s]) ? h : 0.f;
    __syncthreads();

    // masked partial for output row s (overlaps other threads' STAGE polling)
    if (t >= 512 && t < 512 + HPB) {
      const int jl = t - 512;
      float ps = 0.f;
      #pragma unroll
      for (int b = 0; b < BPG; b++) ps += s_red[b * HPB + jl];
      pp[(((size_t)s * GRPS + grp) * MEMB + m) * HPB + jl] = ps;
    }

    if (s == TST - 1) break;

    STAGE(s + 1);      // own slice from LDS; remote slices self-validating poll
    __syncthreads();
  }
}

// ---------------- masked batch-mean + FC ----------------
__global__ void k_out(const float* __restrict__ pp, const int* __restrict__ lens,
                      const float* __restrict__ fcW, const float* __restrict__ fcb,
                      float* __restrict__ out) {
  const int i = blockIdx.x, t = threadIdx.x;
  __shared__ float s_fc[HID];
  const int cnt = min(lens[i], NB);
  const int m = t >> 6, jl = t & 63;             // hid = t
  float a = 0.f;
  const float* base = pp + ((size_t)i * GRPS * MEMB + m) * HPB + jl;
  #pragma unroll 4
  for (int g = 0; g < GRPS; g++) a += base[(size_t)g * MEMB * HPB];
  s_fc[t] = a / (float)cnt;
  __syncthreads();
  for (int n = t; n < NCLS; n += 256) {
    float acc = fcb[n];
    const float4* w4 = (const float4*)(fcW + (size_t)n * HID);
    #pragma unroll 8
    for (int k4 = 0; k4 < HID / 4; k4++) {
      const float4 wv = w4[k4];
      acc = fmaf(s_fc[4*k4+0], wv.x, acc);
      acc = fmaf(s_fc[4*k4+1], wv.y, acc);
      acc = fmaf(s_fc[4*k4+2], wv.z, acc);
      acc = fmaf(s_fc[4*k4+3], wv.w, acc);
    }
    out[(size_t)i * NCLS + n] = acc;
  }
}

extern "C" void kernel_launch(void* const* d_in, const int* in_sizes, int n_in,
                              void* d_out, int out_size, void* d_ws, size_t ws_size,
                              hipStream_t stream) {
  const float* x    = (const float*)d_in[0];
  const int*   lens = (const int*)  d_in[1];
  const float* Wih  = (const float*)d_in[2];
  const float* Whh  = (const float*)d_in[3];
  const float* bih  = (const float*)d_in[4];
  const float* bhh  = (const float*)d_in[5];
  const float* w1h  = (const float*)d_in[6];
  const float* w2h  = (const float*)d_in[7];
  const float* w1c  = (const float*)d_in[8];
  const float* w2c  = (const float*)d_in[9];
  const float* fcW  = (const float*)d_in[10];
  const float* fcb  = (const float*)d_in[11];
  float* out = (float*)d_out;

  char* ws = (char*)d_ws;
  float* sums = (float*)(ws + WS_SUMS);
  u64*   hex0 = (u64*)  (ws + WS_HEX0);
  u64*   hex  = (u64*)  (ws + WS_HEX);
  float* c0   = (float*)(ws + WS_C0);
  float* pp   = (float*)(ws + WS_PP);

  // zero the tagged ring every call: stale tags from a previous replay would
  // falsely validate (tags repeat across calls)
  hipMemsetAsync(hex, 0, 2 * NB * 64 * sizeof(u64), stream);
  k_segsum<<<NB, 256, 0, stream>>>(x, lens, sums);
  k_init  <<<NB, 256, 0, stream>>>(sums, w1h, w2h, w1c, w2c, hex0, c0);
  k_lstm  <<<GRPS * MEMB, 1024, 0, stream>>>(x, lens, Wih, Whh, bih, bhh, c0, hex0, hex, pp);
  k_out   <<<NB, 256, 0, stream>>>(pp, lens, fcW, fcb, out);
}